// Round 8
// baseline (311.994 us; speedup 1.0000x reference)
//
#include <hip/hip_runtime.h>
#include <hip/hip_bf16.h>
#include <stdint.h>

// All FLOAT32 I/O. W converted to bf16 in a small pre-pass; X (q,k,v) read
// as f32 DIRECTLY by qkv_gemm's reg-staged pipeline (convert in-register
// before ds_write — staging data passes through VGPRs anyway).
// GEMMs: T14 reg-staged pipeline (loads for tile t+1 issued at t, consumed
// at t+1 after barrier + compute phase). attn: flash, K-SPLIT x2, fixed-base
// softmax; merge fused into out_gemm. attn v13: KBLK=128 — two independent
// S->softmax->PV chains per barrier pair (ILP; TLP proven null in R4).
// History: v8 FAILED (launch_bounds spill); v10 NULL (ksplit x4);
// v12 FAILED (GLDS16 dbuf: drain still in-iter); v11 NULL (V^T scatter was
// L2-absorbed, not a 40us cost).
#define SEQ     2048
#define NBATCH  2
#define DMODEL  1024
#define NH      16
#define DKH     64

typedef __bf16 bf16;
typedef __attribute__((ext_vector_type(8))) __bf16 bf16x8;
typedef __attribute__((ext_vector_type(4))) __bf16 bf16x4;
typedef __attribute__((ext_vector_type(4))) float  f32x4;

static __device__ __forceinline__ f32x4 mfma16(bf16x8 a, bf16x8 b, f32x4 c) {
    return __builtin_amdgcn_mfma_f32_16x16x32_bf16(a, b, c, 0, 0, 0);
}

// in-place cross-lane row swaps (gfx950)
#define PL32SWAP(a, b) asm("v_permlane32_swap_b32 %0, %1" : "+v"(a), "+v"(b))
#define PL16SWAP(a, b) asm("v_permlane16_swap_b32 %0, %1" : "+v"(a), "+v"(b))

// ---------------------------------------------------------------------------
// Kernel 0: f32 -> bf16 convert for W (wq,wk,wv,wo); y=4 packs mask
// [n,1,s,s] int32 -> bitmask uint64 [n*s, s/64]. (X converted inside qkv.)
// ---------------------------------------------------------------------------
__global__ __launch_bounds__(256) void cvt_all_k(const float* __restrict__ wq,
                                                 const float* __restrict__ wk,
                                                 const float* __restrict__ wv,
                                                 const float* __restrict__ wo,
                                                 const int* __restrict__ mask,
                                                 bf16* __restrict__ wqb,
                                                 bf16* __restrict__ wkb,
                                                 bf16* __restrict__ wvb,
                                                 bf16* __restrict__ wob,
                                                 unsigned long long* __restrict__ mbits) {
    if (blockIdx.y == 4) {  // mask pack
        const int nwords = NBATCH * SEQ * (SEQ / 64);
        int wave  = (blockIdx.x * blockDim.x + threadIdx.x) >> 6;
        int lane  = threadIdx.x & 63;
        int nwtot = (gridDim.x * blockDim.x) >> 6;
        for (int w = wave; w < nwords; w += nwtot) {
            int m = mask[(size_t)w * 64 + lane];
            unsigned long long b = __ballot(m != 0);
            if (lane == 0) mbits[w] = b;
        }
        return;
    }
    const float* src; bf16* dst;
    switch (blockIdx.y) {
        case 0: src = wq; dst = wqb; break;
        case 1: src = wk; dst = wkb; break;
        case 2: src = wv; dst = wvb; break;
        default: src = wo; dst = wob; break;
    }
    const int NW4 = (DMODEL * DMODEL) / 4;
    int stride = gridDim.x * blockDim.x;
    for (int i = blockIdx.x * blockDim.x + threadIdx.x; i < NW4; i += stride) {
        f32x4 f = ((const f32x4*)src)[i];
        bf16x4 o;
#pragma unroll
        for (int j = 0; j < 4; j++) o[j] = (bf16)f[j];
        ((bf16x4*)dst)[i] = o;
    }
}

// ---------------------------------------------------------------------------
// Kernel 2: QKV projection. 128x128 tiles, reg-staged T14 pipeline. X read
// as FLOAT32 (converted to bf16 in-register before ds_write). W read bf16.
// z=0:Q (pre-scaled by 0.125*log2e) z=1:K -> [n,h,s,64]; z=2:V -> [n,h,64,s]
// via in-register transposed accumulate (operand swap) for coalesced stores.
// ---------------------------------------------------------------------------
__global__ __launch_bounds__(256) void qkv_gemm(const float* __restrict__ Xq,
                                                const float* __restrict__ Xk,
                                                const float* __restrict__ Xv,
                                                const bf16* __restrict__ Wq,
                                                const bf16* __restrict__ Wk,
                                                const bf16* __restrict__ Wv,
                                                bf16* __restrict__ Qo,
                                                bf16* __restrict__ Ko,
                                                bf16* __restrict__ Vto) {
    __shared__ bf16 As[128 * 32], Bs[128 * 32];
    const int z = blockIdx.z;
    const float* A = (z == 0) ? Xq : (z == 1) ? Xk : Xv;
    const bf16*  W = (z == 0) ? Wq : (z == 1) ? Wk : Wv;
    const int bm = blockIdx.x * 128, bn = blockIdx.y * 128;
    const int tid = threadIdx.x, wave = tid >> 6, lane = tid & 63;
    const int wm = wave >> 1, wn = wave & 1, lo = lane & 15, hi = lane >> 4;

    const int r0 = wave * 32 + (lane >> 2);
    const int c8 = (lane & 3) * 8;
    const float* Ag = A + (size_t)(bm + r0) * DMODEL + c8;
    const bf16*  Bg = W + (size_t)(bn + r0) * DMODEL + c8;
    bf16* lA = &As[wave * 1024 + (lane >> 2) * 32 + (lane & 3) * 8];
    bf16* lB = &Bs[wave * 1024 + (lane >> 2) * 32 + (lane & 3) * 8];

    f32x4 acc[4][4];
#pragma unroll
    for (int i = 0; i < 4; i++)
#pragma unroll
        for (int j = 0; j < 4; j++) acc[i][j] = 0.0f;

    // prologue: prefetch k-tile 0 (A as f32, B as bf16)
    f32x4 fa0 = *(const f32x4*)(Ag);
    f32x4 fa1 = *(const f32x4*)(Ag + 4);
    f32x4 fa2 = *(const f32x4*)(Ag + (size_t)16 * DMODEL);
    f32x4 fa3 = *(const f32x4*)(Ag + (size_t)16 * DMODEL + 4);
    bf16x8 rb0 = *(const bf16x8*)(Bg);
    bf16x8 rb1 = *(const bf16x8*)(Bg + (size_t)16 * DMODEL);

#pragma unroll 1
    for (int k0 = 0; k0 < DMODEL; k0 += 32) {
        __syncthreads();   // all waves done reading LDS from previous iter
        bf16x8 wa0, wa1;
#pragma unroll
        for (int j = 0; j < 4; j++) {
            wa0[j] = (bf16)fa0[j]; wa0[4 + j] = (bf16)fa1[j];
            wa1[j] = (bf16)fa2[j]; wa1[4 + j] = (bf16)fa3[j];
        }
        *(bf16x8*)lA         = wa0;
        *(bf16x8*)(lA + 512) = wa1;
        *(bf16x8*)lB         = rb0;
        *(bf16x8*)(lB + 512) = rb1;
        if (k0 + 32 < DMODEL) {  // issue next-tile loads; consumed next iter
            fa0 = *(const f32x4*)(Ag + k0 + 32);
            fa1 = *(const f32x4*)(Ag + k0 + 36);
            fa2 = *(const f32x4*)(Ag + k0 + 32 + (size_t)16 * DMODEL);
            fa3 = *(const f32x4*)(Ag + k0 + 36 + (size_t)16 * DMODEL);
            rb0 = *(const bf16x8*)(Bg + k0 + 32);
            rb1 = *(const bf16x8*)(Bg + k0 + 32 + (size_t)16 * DMODEL);
        }
        __syncthreads();   // LDS writes visible

        bf16x8 a[4], b[4];
#pragma unroll
        for (int t = 0; t < 4; t++) {
            a[t] = *(const bf16x8*)&As[(wm * 64 + t * 16 + lo) * 32 + hi * 8];
            b[t] = *(const bf16x8*)&Bs[(wn * 64 + t * 16 + lo) * 32 + hi * 8];
        }
        if (z < 2) {
#pragma unroll
            for (int tm = 0; tm < 4; tm++)
#pragma unroll
                for (int tn = 0; tn < 4; tn++)
                    acc[tm][tn] = mfma16(a[tm], b[tn], acc[tm][tn]);
        } else {
            // transposed accumulate: acc[tm][tn] = C^T tile (rows=o, cols=m)
#pragma unroll
            for (int tm = 0; tm < 4; tm++)
#pragma unroll
                for (int tn = 0; tn < 4; tn++)
                    acc[tm][tn] = mfma16(b[tn], a[tm], acc[tm][tn]);
        }
    }

    if (z < 2) {
        bf16* O = (z == 0) ? Qo : Ko;
        const float qscale = (z == 0) ? 0.18033688f : 1.0f;  // 0.125 * log2(e)
#pragma unroll
        for (int tm = 0; tm < 4; tm++)
#pragma unroll
            for (int tn = 0; tn < 4; tn++)
#pragma unroll
                for (int r = 0; r < 4; r++) {
                    int m = bm + wm * 64 + tm * 16 + hi * 4 + r;
                    int o = bn + wn * 64 + tn * 16 + lo;
                    int nidx = m >> 11, sq = m & 2047;
                    int hh = o >> 6, d = o & 63;
                    O[(((size_t)nidx * NH + hh) * SEQ + sq) * DKH + d] = (bf16)(acc[tm][tn][r] * qscale);
                }
    } else {
        // acc is C^T: row (hi*4+r) -> o (h,d); col (lo) -> m (n,sq).
#pragma unroll
        for (int tm = 0; tm < 4; tm++)
#pragma unroll
            for (int tn = 0; tn < 4; tn++)
#pragma unroll
                for (int r = 0; r < 4; r++) {
                    int o = bn + wn * 64 + tn * 16 + hi * 4 + r;
                    int m = bm + wm * 64 + tm * 16 + lo;
                    int nidx = m >> 11, sq = m & 2047;
                    int hh = o >> 6, d = o & 63;
                    Vto[(((size_t)nidx * NH + hh) * DKH + d) * SEQ + sq] = (bf16)acc[tm][tn][r];
                }
    }
}

// ---------------------------------------------------------------------------
// Kernel 3: flash attention v13 — QBLK=128 + KBLK=128: TWO independent 64-k
// tiles (S->softmax->PV chains) per barrier pair -> ILP inside the barrier
// section (TLP was proven null). Swapped QK^T + in-register softmax.
// K-SPLIT x ksn. LDS: Ks[128][72] + Vs[64][136] = 35.8 KB -> 4 blocks/CU.
// ---------------------------------------------------------------------------
__global__ __launch_bounds__(256, 4) void attn_k(const bf16* __restrict__ Q,
                                                 const bf16* __restrict__ K,
                                                 const bf16* __restrict__ Vt,
                                                 const unsigned long long* __restrict__ mbits,
                                                 bf16* __restrict__ Op0,
                                                 bf16* __restrict__ Op1,
                                                 float* __restrict__ Lp,
                                                 int ksrange) {
    __shared__ bf16 Ks[128 * 72];
    __shared__ bf16 Vs[64 * 136];

    const int bid = blockIdx.x;
    const int xcd = bid & 7, j = bid >> 3;        // j: 0..(grid/8-1)
    const int hd = xcd * 4 + (j & 3);             // head index 0..31 (= n*16+h)
    const int qb = (j >> 2) & 15;                 // q-block 0..15 (128 rows each)
    const int ks = j >> 6;                        // k-split index (0..ksn-1)
    const int n = hd >> 4, h = hd & 15;

    const int tid = threadIdx.x, wave = tid >> 6, lane = tid & 63;
    const int lo = lane & 15, hi = lane >> 4;

    const size_t headoff = (size_t)hd * SEQ * DKH;
    const bf16* Qh = Q + headoff;
    const bf16* Kh = K + headoff;
    const bf16* Vh = Vt + headoff;   // [64][2048]

    const int qrowA = qb * 128 + wave * 16 + lo;
    const int qrowB = qrowA + 64;
    const bf16x8 aq0A = *(const bf16x8*)(Qh + (size_t)qrowA * DKH + hi * 8);
    const bf16x8 aq1A = *(const bf16x8*)(Qh + (size_t)qrowA * DKH + 32 + hi * 8);
    const bf16x8 aq0B = *(const bf16x8*)(Qh + (size_t)qrowB * DKH + hi * 8);
    const bf16x8 aq1B = *(const bf16x8*)(Qh + (size_t)qrowB * DKH + 32 + hi * 8);

    bf16x8 ones;
#pragma unroll
    for (int i = 0; i < 8; i++) ones[i] = (bf16)1.0f;

    f32x4 oaccA[4], oaccB[4];
#pragma unroll
    for (int t = 0; t < 4; t++) { oaccA[t] = 0.0f; oaccB[t] = 0.0f; }
    f32x4 laccA; laccA = 0.0f;
    f32x4 laccB; laccB = 0.0f;

    const unsigned long long* mbqA = mbits + ((size_t)n * SEQ + qrowA) * (SEQ / 64);
    const unsigned long long* mbqB = mbits + ((size_t)n * SEQ + qrowB) * (SEQ / 64);

    const int kbeg = ks * ksrange, kend = kbeg + ksrange;

    const int srow = tid >> 3, sseg = tid & 7;   // 32 rows x 64 cols per store round
    const bf16* Kg = Kh + (size_t)srow * DKH + sseg * 8;
    const bf16* Vg = Vh + (size_t)srow * SEQ + sseg * 8;

    // preload first 128-k tile of this k-range into registers
    bf16x8 rk0 = *(const bf16x8*)(Kg + (size_t)(kbeg)      * DKH);
    bf16x8 rk1 = *(const bf16x8*)(Kg + (size_t)(kbeg + 32) * DKH);
    bf16x8 rk2 = *(const bf16x8*)(Kg + (size_t)(kbeg + 64) * DKH);
    bf16x8 rk3 = *(const bf16x8*)(Kg + (size_t)(kbeg + 96) * DKH);
    bf16x8 rv0 = *(const bf16x8*)(Vg + kbeg);
    bf16x8 rv1 = *(const bf16x8*)(Vg + (size_t)32 * SEQ + kbeg);
    bf16x8 rv2 = *(const bf16x8*)(Vg + kbeg + 64);
    bf16x8 rv3 = *(const bf16x8*)(Vg + (size_t)32 * SEQ + kbeg + 64);
    unsigned long long wmA0 = mbqA[(kbeg >> 6)], wmA1 = mbqA[(kbeg >> 6) + 1];
    unsigned long long wmB0 = mbqB[(kbeg >> 6)], wmB1 = mbqB[(kbeg >> 6) + 1];
    unsigned long long wmnA0 = 0, wmnA1 = 0, wmnB0 = 0, wmnB1 = 0;

    union FragU { uint32_t u[4]; bf16x8 v; };

    // one 64-k tile: S^T (both q-subtiles) -> masked exp2 -> pack/permlane ->
    // PV accumulate. koff selects tile row/col base inside Ks/Vs.
    auto tile = [&](int koff, unsigned long long wmA, unsigned long long wmB) {
        unsigned wloA = (unsigned)(wmA >> (hi * 4));
        unsigned whiA = (unsigned)(wmA >> (hi * 4 + 32));
        unsigned wloB = (unsigned)(wmB >> (hi * 4));
        unsigned whiB = (unsigned)(wmB >> (hi * 4 + 32));
        uint32_t pkA[4][2], pkB[4][2];
#pragma unroll
        for (int tn = 0; tn < 4; tn++) {
            const int kr = (koff + tn * 16 + lo) * 72;
            bf16x8 b0 = *(const bf16x8*)&Ks[kr + hi * 8];
            bf16x8 b1 = *(const bf16x8*)&Ks[kr + 32 + hi * 8];
            f32x4 zA; zA = 0.0f;
            zA = mfma16(b0, aq0A, zA);
            zA = mfma16(b1, aq1A, zA);
            f32x4 zB; zB = 0.0f;
            zB = mfma16(b0, aq0B, zB);
            zB = mfma16(b1, aq1B, zB);
            unsigned wsA = ((tn < 2) ? wloA : whiA) >> ((tn & 1) * 16);
            unsigned wsB = ((tn < 2) ? wloB : whiB) >> ((tn & 1) * 16);
            float pvA[4], pvB[4];
#pragma unroll
            for (int r = 0; r < 4; r++) {
                float eA = __builtin_amdgcn_exp2f(zA[r]);
                pvA[r] = ((wsA >> r) & 1u) ? eA : 0.0f;
                float eB = __builtin_amdgcn_exp2f(zB[r]);
                pvB[r] = ((wsB >> r) & 1u) ? eB : 0.0f;
            }
            asm("v_cvt_pk_bf16_f32 %0, %1, %2" : "=v"(pkA[tn][0]) : "v"(pvA[0]), "v"(pvA[1]));
            asm("v_cvt_pk_bf16_f32 %0, %1, %2" : "=v"(pkA[tn][1]) : "v"(pvA[2]), "v"(pvA[3]));
            asm("v_cvt_pk_bf16_f32 %0, %1, %2" : "=v"(pkB[tn][0]) : "v"(pvB[0]), "v"(pvB[1]));
            asm("v_cvt_pk_bf16_f32 %0, %1, %2" : "=v"(pkB[tn][1]) : "v"(pvB[2]), "v"(pvB[3]));
        }

        bf16x8 ap0A, ap1A, ap0B, ap1B;
        {
            uint32_t d00 = pkA[0][0], d02 = pkA[1][0];
            PL32SWAP(d00, d02); PL16SWAP(d00, d02);
            uint32_t d01 = pkA[0][1], d03 = pkA[1][1];
            PL32SWAP(d01, d03); PL16SWAP(d01, d03);
            uint32_t d10 = pkA[2][0], d12 = pkA[3][0];
            PL32SWAP(d10, d12); PL16SWAP(d10, d12);
            uint32_t d11 = pkA[2][1], d13 = pkA[3][1];
            PL32SWAP(d11, d13); PL16SWAP(d11, d13);
            FragU f0, f1;
            f0.u[0] = d00; f0.u[1] = d01; f0.u[2] = d02; f0.u[3] = d03;
            f1.u[0] = d10; f1.u[1] = d11; f1.u[2] = d12; f1.u[3] = d13;
            ap0A = f0.v; ap1A = f1.v;
        }
        {
            uint32_t d00 = pkB[0][0], d02 = pkB[1][0];
            PL32SWAP(d00, d02); PL16SWAP(d00, d02);
            uint32_t d01 = pkB[0][1], d03 = pkB[1][1];
            PL32SWAP(d01, d03); PL16SWAP(d01, d03);
            uint32_t d10 = pkB[2][0], d12 = pkB[3][0];
            PL32SWAP(d10, d12); PL16SWAP(d10, d12);
            uint32_t d11 = pkB[2][1], d13 = pkB[3][1];
            PL32SWAP(d11, d13); PL16SWAP(d11, d13);
            FragU f0, f1;
            f0.u[0] = d00; f0.u[1] = d01; f0.u[2] = d02; f0.u[3] = d03;
            f1.u[0] = d10; f1.u[1] = d11; f1.u[2] = d12; f1.u[3] = d13;
            ap0B = f0.v; ap1B = f1.v;
        }

#pragma unroll
        for (int td = 0; td < 4; td++) {
            bf16x8 b0 = *(const bf16x8*)&Vs[(td * 16 + lo) * 136 + koff + hi * 8];
            bf16x8 b1 = *(const bf16x8*)&Vs[(td * 16 + lo) * 136 + koff + 32 + hi * 8];
            oaccA[td] = mfma16(ap0A, b0, oaccA[td]);
            oaccA[td] = mfma16(ap1A, b1, oaccA[td]);
            oaccB[td] = mfma16(ap0B, b0, oaccB[td]);
            oaccB[td] = mfma16(ap1B, b1, oaccB[td]);
        }
        laccA = mfma16(ap0A, ones, laccA);
        laccA = mfma16(ap1A, ones, laccA);
        laccB = mfma16(ap0B, ones, laccB);
        laccB = mfma16(ap1B, ones, laccB);
    };

#pragma unroll 1
    for (int k0 = kbeg; k0 < kend; k0 += 128) {
        __syncthreads();
        *(bf16x8*)&Ks[(srow)      * 72 + sseg * 8] = rk0;
        *(bf16x8*)&Ks[(srow + 32) * 72 + sseg * 8] = rk1;
        *(bf16x8*)&Ks[(srow + 64) * 72 + sseg * 8] = rk2;
        *(bf16x8*)&Ks[(srow + 96) * 72 + sseg * 8] = rk3;
        *(bf16x8*)&Vs[(srow)      * 136 + sseg * 8]      = rv0;
        *(bf16x8*)&Vs[(srow + 32) * 136 + sseg * 8]      = rv1;
        *(bf16x8*)&Vs[(srow)      * 136 + 64 + sseg * 8] = rv2;
        *(bf16x8*)&Vs[(srow + 32) * 136 + 64 + sseg * 8] = rv3;
        if (k0 + 128 < kend) {  // prefetch next 128-k tile (covered by compute)
            rk0 = *(const bf16x8*)(Kg + (size_t)(k0 + 128) * DKH);
            rk1 = *(const bf16x8*)(Kg + (size_t)(k0 + 160) * DKH);
            rk2 = *(const bf16x8*)(Kg + (size_t)(k0 + 192) * DKH);
            rk3 = *(const bf16x8*)(Kg + (size_t)(k0 + 224) * DKH);
            rv0 = *(const bf16x8*)(Vg + k0 + 128);
            rv1 = *(const bf16x8*)(Vg + (size_t)32 * SEQ + k0 + 128);
            rv2 = *(const bf16x8*)(Vg + k0 + 192);
            rv3 = *(const bf16x8*)(Vg + (size_t)32 * SEQ + k0 + 192);
            wmnA0 = mbqA[(k0 >> 6) + 2]; wmnA1 = mbqA[(k0 >> 6) + 3];
            wmnB0 = mbqB[(k0 >> 6) + 2]; wmnB1 = mbqB[(k0 >> 6) + 3];
        }
        __syncthreads();

        tile(0,  wmA0, wmB0);   // two independent chains inside one barrier
        tile(64, wmA1, wmB1);   // section: scheduler overlaps S1 with SM0

        wmA0 = wmnA0; wmA1 = wmnA1;
        wmB0 = wmnB0; wmB1 = wmnB1;
    }

    // epilogue: write bf16 partial O [n,q,h*64+d] and f32 partial l [ks][n,h,q]
    bf16* Op = ks ? Op1 : Op0;
#pragma unroll
    for (int td = 0; td < 4; td++)
#pragma unroll
        for (int r = 0; r < 4; r++) {
            int qA = qb * 128 + wave * 16 + hi * 4 + r;
            int qB = qA + 64;
            int d = td * 16 + lo;
            Op[((size_t)n * SEQ + qA) * DMODEL + h * 64 + d] = (bf16)oaccA[td][r];
            Op[((size_t)n * SEQ + qB) * DMODEL + h * 64 + d] = (bf16)oaccB[td][r];
        }
    if (lo == 0) {
#pragma unroll
        for (int r = 0; r < 4; r++) {
            int qA = qb * 128 + wave * 16 + hi * 4 + r;
            int qB = qA + 64;
            size_t base = (size_t)ks * (NBATCH * NH * SEQ) + ((size_t)(n * NH + h) * SEQ);
            Lp[base + qA] = laccA[r];
            Lp[base + qB] = laccB[r];
        }
    }
}

// ---------------------------------------------------------------------------
// Kernel 4: out = ((o0+o1)/sum(l)) @ Wo^T + bo, FP32 out. MERGE FUSED into
// the A-staging (h = k0>>6 uniform per K-step). Reg-staged T14 pipeline.
// ---------------------------------------------------------------------------
__global__ __launch_bounds__(256) void out_gemm(const bf16* __restrict__ o0,
                                                const bf16* __restrict__ o1,
                                                const float* __restrict__ lp,
                                                const bf16* __restrict__ W,
                                                const float* __restrict__ bias,
                                                float* __restrict__ Out) {
    __shared__ bf16 As[128 * 32], Bs[128 * 32];
    const int bm = blockIdx.x * 128, bn = blockIdx.y * 128;
    const int tid = threadIdx.x, wave = tid >> 6, lane = tid & 63;
    const int wm = wave >> 1, wn = wave & 1, lo = lane & 15, hi = lane >> 4;

    const int r0 = wave * 32 + (lane >> 2);
    const int c8 = (lane & 3) * 8;
    const int m1 = bm + r0, m2 = m1 + 16;
    const size_t aoff1 = (size_t)m1 * DMODEL + c8;
    const size_t aoff2 = (size_t)m2 * DMODEL + c8;
    const bf16* Bg = W + (size_t)(bn + r0) * DMODEL + c8;
    const int NL = NBATCH * NH * SEQ;
    const int li1b = (m1 >> 11) * (NH * SEQ) + (m1 & 2047);
    const int li2b = (m2 >> 11) * (NH * SEQ) + (m2 & 2047);
    bf16* lA = &As[wave * 1024 + (lane >> 2) * 32 + (lane & 3) * 8];
    bf16* lB = &Bs[wave * 1024 + (lane >> 2) * 32 + (lane & 3) * 8];

    f32x4 acc[4][4];
#pragma unroll
    for (int i = 0; i < 4; i++)
#pragma unroll
        for (int j = 0; j < 4; j++) acc[i][j] = 0.0f;

    // prologue: prefetch k-tile 0 (h = 0)
    bf16x8 px0 = *(const bf16x8*)(o0 + aoff1);
    bf16x8 py0 = *(const bf16x8*)(o1 + aoff1);
    bf16x8 px1 = *(const bf16x8*)(o0 + aoff2);
    bf16x8 py1 = *(const bf16x8*)(o1 + aoff2);
    bf16x8 pb0 = *(const bf16x8*)(Bg);
    bf16x8 pb1 = *(const bf16x8*)(Bg + (size_t)16 * DMODEL);
    float pl1a = lp[li1b], pl1b = lp[NL + li1b];
    float pl2a = lp[li2b], pl2b = lp[NL + li2b];

#pragma unroll 1
    for (int k0 = 0; k0 < DMODEL; k0 += 32) {
        __syncthreads();
        float rl1 = 1.0f / (pl1a + pl1b);
        float rl2 = 1.0f / (pl2a + pl2b);
        bf16x8 wa0, wa1;
#pragma unroll
        for (int jj = 0; jj < 8; jj++) {
            wa0[jj] = (bf16)(((float)px0[jj] + (float)py0[jj]) * rl1);
            wa1[jj] = (bf16)(((float)px1[jj] + (float)py1[jj]) * rl2);
        }
        *(bf16x8*)lA         = wa0;
        *(bf16x8*)(lA + 512) = wa1;
        *(bf16x8*)lB         = pb0;
        *(bf16x8*)(lB + 512) = pb1;
        if (k0 + 32 < DMODEL) {  // prefetch next k-tile (h = (k0+32)>>6)
            int h = (k0 + 32) >> 6;
            px0 = *(const bf16x8*)(o0 + aoff1 + k0 + 32);
            py0 = *(const bf16x8*)(o1 + aoff1 + k0 + 32);
            px1 = *(const bf16x8*)(o0 + aoff2 + k0 + 32);
            py1 = *(const bf16x8*)(o1 + aoff2 + k0 + 32);
            pb0 = *(const bf16x8*)(Bg + k0 + 32);
            pb1 = *(const bf16x8*)(Bg + k0 + 32 + (size_t)16 * DMODEL);
            int li1 = li1b + h * SEQ, li2 = li2b + h * SEQ;
            pl1a = lp[li1]; pl1b = lp[NL + li1];
            pl2a = lp[li2]; pl2b = lp[NL + li2];
        }
        __syncthreads();

        bf16x8 a[4], b[4];
#pragma unroll
        for (int t = 0; t < 4; t++) {
            a[t] = *(const bf16x8*)&As[(wm * 64 + t * 16 + lo) * 32 + hi * 8];
            b[t] = *(const bf16x8*)&Bs[(wn * 64 + t * 16 + lo) * 32 + hi * 8];
        }
#pragma unroll
        for (int tm = 0; tm < 4; tm++)
#pragma unroll
            for (int tn = 0; tn < 4; tn++)
                acc[tm][tn] = mfma16(a[tm], b[tn], acc[tm][tn]);
    }

#pragma unroll
    for (int tm = 0; tm < 4; tm++)
#pragma unroll
        for (int tn = 0; tn < 4; tn++) {
            int o = bn + wn * 64 + tn * 16 + lo;
            float bv = bias[o];
#pragma unroll
            for (int r = 0; r < 4; r++) {
                int m = bm + wm * 64 + tm * 16 + hi * 4 + r;
                Out[(size_t)m * DMODEL + o] = acc[tm][tn][r] + bv;
            }
        }
}

// ---------------------------------------------------------------------------
extern "C" void kernel_launch(void* const* d_in, const int* in_sizes, int n_in,
                              void* d_out, int out_size, void* d_ws, size_t ws_size,
                              hipStream_t stream) {
    const float* value = (const float*)d_in[0];
    const float* key   = (const float*)d_in[1];
    const float* query = (const float*)d_in[2];
    const int*   mask  = (const int*)d_in[3];
    const float* Wq    = (const float*)d_in[4];
    const float* Wk    = (const float*)d_in[5];
    const float* Wv    = (const float*)d_in[6];
    const float* Wo    = (const float*)d_in[7];
    const float* bo    = (const float*)d_in[8];
    float* out = (float*)d_out;

    char* ws = (char*)d_ws;
    bf16* Qws = (bf16*)(ws);                         // 8 MB [n,h,s,64]
    bf16* Kws = (bf16*)(ws + (8u  << 20));           // 8 MB [n,h,s,64]
    bf16* Vt  = (bf16*)(ws + (16u << 20));           // 8 MB [n,h,64,s]
    bf16* Op0 = (bf16*)(ws + (24u << 20));           // 8 MB attn partial 0
    bf16* Op1 = (bf16*)(ws + (32u << 20));           // 8 MB attn partial 1
    bf16* Wqb = (bf16*)(ws + (48u << 20));           // 2 MB; after qkv: l_part (512KB)
    bf16* Wkb = (bf16*)(ws + (50u << 20));           // 2 MB
    bf16* Wvb = (bf16*)(ws + (52u << 20));           // 2 MB
    bf16* Wob = (bf16*)(ws + (54u << 20));           // 2 MB (live until out_gemm)
    unsigned long long* mbits = (unsigned long long*)(ws + (56u << 20));  // 1 MB
    float* Lp  = (float*)Wqb;

    // K-SPLIT x2 (x4 measured NULL in R4 — attn is not TLP-bound)
    const int  ksn     = 2;
    const int  ksrange = SEQ / ksn;
    const int  attn_grid = 32 * 16 * ksn;            // heads * q-blocks * k-splits

    cvt_all_k<<<dim3(1024, 5), 256, 0, stream>>>(Wq, Wk, Wv, Wo, mask,
                                                 Wqb, Wkb, Wvb, Wob, mbits);
    qkv_gemm<<<dim3(32, 8, 3), 256, 0, stream>>>(query, key, value, Wqb, Wkb, Wvb, Qws, Kws, Vt);
    attn_k<<<attn_grid, 256, 0, stream>>>(Qws, Kws, Vt, mbits, Op0, Op1, Lp, ksrange);
    out_gemm<<<dim3(32, 8), 256, 0, stream>>>(Op0, Op1, Lp, Wob, bo, out);
}

// Round 10
// 274.905 us; speedup vs baseline: 1.1349x; 1.1349x over previous
//
#include <hip/hip_runtime.h>
#include <hip/hip_bf16.h>
#include <stdint.h>

// All FLOAT32 I/O. bf16 compute via convert pre-pass.
// GEMMs: T14 reg-staged pipeline, retiled 128x64 (v14): doubles blocks/CU
// (out: 1->2, qkv: 3->6) — pure TLP for the latency-idle regime (R5: qkv
// was 84% idle; out runs 1 wave/SIMD). attn: flash, K-SPLIT x2, fixed-base
// softmax, KBLK=64 (KBLK=128 spilled: WRITE 17->147MB, R8); merge fused
// into out_gemm.
// History: v8/v13 FAILED (reg pressure -> scratch spills; tripwire =
// WRITE_SIZE); v10 NULL (ksplit x4, attn not TLP-bound); v12 FAILED (GLDS16
// dbuf drains in-iter); v13b suspect (f32-X fusion +14us on latency-bound
// qkv — reverted). R9: bench infra failure (trio nursery), kernel audited
// (bounds/coverage verified by hand) and resubmitted unchanged.
#define SEQ     2048
#define NBATCH  2
#define DMODEL  1024
#define NH      16
#define DKH     64

typedef __bf16 bf16;
typedef __attribute__((ext_vector_type(8))) __bf16 bf16x8;
typedef __attribute__((ext_vector_type(4))) __bf16 bf16x4;
typedef __attribute__((ext_vector_type(4))) float  f32x4;

static __device__ __forceinline__ f32x4 mfma16(bf16x8 a, bf16x8 b, f32x4 c) {
    return __builtin_amdgcn_mfma_f32_16x16x32_bf16(a, b, c, 0, 0, 0);
}

// in-place cross-lane row swaps (gfx950)
#define PL32SWAP(a, b) asm("v_permlane32_swap_b32 %0, %1" : "+v"(a), "+v"(b))
#define PL16SWAP(a, b) asm("v_permlane16_swap_b32 %0, %1" : "+v"(a), "+v"(b))

// ---------------------------------------------------------------------------
// Kernel 0: f32 -> bf16 convert for X (q,k,v) and W (wq,wk,wv,wo); y=7 packs
// mask [n,1,s,s] int32 -> bitmask uint64 [n*s, s/64].
// ---------------------------------------------------------------------------
__global__ __launch_bounds__(256) void cvt_all_k(const float* __restrict__ q,
                                                 const float* __restrict__ k,
                                                 const float* __restrict__ v,
                                                 const float* __restrict__ wq,
                                                 const float* __restrict__ wk,
                                                 const float* __restrict__ wv,
                                                 const float* __restrict__ wo,
                                                 const int* __restrict__ mask,
                                                 bf16* __restrict__ qb, bf16* __restrict__ kb,
                                                 bf16* __restrict__ vb, bf16* __restrict__ wqb,
                                                 bf16* __restrict__ wkb, bf16* __restrict__ wvb,
                                                 bf16* __restrict__ wob,
                                                 unsigned long long* __restrict__ mbits) {
    if (blockIdx.y == 7) {  // mask pack
        const int nwords = NBATCH * SEQ * (SEQ / 64);
        int wave  = (blockIdx.x * blockDim.x + threadIdx.x) >> 6;
        int lane  = threadIdx.x & 63;
        int nwtot = (gridDim.x * blockDim.x) >> 6;
        for (int w = wave; w < nwords; w += nwtot) {
            int m = mask[(size_t)w * 64 + lane];
            unsigned long long b = __ballot(m != 0);
            if (lane == 0) mbits[w] = b;
        }
        return;
    }
    const float* src; bf16* dst; int n4;
    const int NX4 = (NBATCH * SEQ * DMODEL) / 4, NW4 = (DMODEL * DMODEL) / 4;
    switch (blockIdx.y) {
        case 0: src = q;  dst = qb;  n4 = NX4; break;
        case 1: src = k;  dst = kb;  n4 = NX4; break;
        case 2: src = v;  dst = vb;  n4 = NX4; break;
        case 3: src = wq; dst = wqb; n4 = NW4; break;
        case 4: src = wk; dst = wkb; n4 = NW4; break;
        case 5: src = wv; dst = wvb; n4 = NW4; break;
        default: src = wo; dst = wob; n4 = NW4; break;
    }
    int stride = gridDim.x * blockDim.x;
    for (int i = blockIdx.x * blockDim.x + threadIdx.x; i < n4; i += stride) {
        f32x4 f = ((const f32x4*)src)[i];
        bf16x4 o;
#pragma unroll
        for (int j = 0; j < 4; j++) o[j] = (bf16)f[j];
        ((bf16x4*)dst)[i] = o;
    }
}

// ---------------------------------------------------------------------------
// Kernel 2: QKV projection. 128x64 tiles (v14), reg-staged T14 pipeline:
// barrier -> ds_write(prefetched regs) -> issue loads for NEXT k-tile ->
// barrier -> ds_read + MFMA. Grid (32,16,3) = 1536 blocks = 6/CU.
// Per-wave output 64x32 (acc[4][2]). z=0:Q (pre-scaled) z=1:K -> [n,h,s,64];
// z=2:V -> [n,h,64,s] via transposed accumulate (operand swap).
// ---------------------------------------------------------------------------
__global__ __launch_bounds__(256) void qkv_gemm(const bf16* __restrict__ Xq,
                                                const bf16* __restrict__ Xk,
                                                const bf16* __restrict__ Xv,
                                                const bf16* __restrict__ Wq,
                                                const bf16* __restrict__ Wk,
                                                const bf16* __restrict__ Wv,
                                                bf16* __restrict__ Qo,
                                                bf16* __restrict__ Ko,
                                                bf16* __restrict__ Vto) {
    __shared__ bf16 As[128 * 32], Bs[64 * 32];
    const int z = blockIdx.z;
    const bf16* A = (z == 0) ? Xq : (z == 1) ? Xk : Xv;
    const bf16* W = (z == 0) ? Wq : (z == 1) ? Wk : Wv;
    const int bm = blockIdx.x * 128, bn = blockIdx.y * 64;
    const int tid = threadIdx.x, wave = tid >> 6, lane = tid & 63;
    const int wm = wave >> 1, wn = wave & 1, lo = lane & 15, hi = lane >> 4;

    const int ra_row = wave * 32 + (lane >> 2);   // A: 4 waves x 32 = 128 rows
    const int rb_row = wave * 16 + (lane >> 2);   // B: 4 waves x 16 = 64 rows
    const int c8 = (lane & 3) * 8;
    const bf16* Ag = A + (size_t)(bm + ra_row) * DMODEL + c8;
    const bf16* Bg = W + (size_t)(bn + rb_row) * DMODEL + c8;
    bf16* lA = &As[ra_row * 32 + c8];
    bf16* lB = &Bs[rb_row * 32 + c8];

    f32x4 acc[4][2];
#pragma unroll
    for (int i = 0; i < 4; i++)
#pragma unroll
        for (int j = 0; j < 2; j++) acc[i][j] = 0.0f;

    // prologue: prefetch k-tile 0 into registers
    bf16x8 ra0 = *(const bf16x8*)(Ag);
    bf16x8 ra1 = *(const bf16x8*)(Ag + (size_t)16 * DMODEL);
    bf16x8 rb0 = *(const bf16x8*)(Bg);

#pragma unroll 1
    for (int k0 = 0; k0 < DMODEL; k0 += 32) {
        __syncthreads();   // all waves done reading LDS from previous iter
        *(bf16x8*)lA         = ra0;
        *(bf16x8*)(lA + 512) = ra1;   // +16 rows
        *(bf16x8*)lB         = rb0;
        if (k0 + 32 < DMODEL) {  // issue next-tile loads; consumed next iter
            ra0 = *(const bf16x8*)(Ag + k0 + 32);
            ra1 = *(const bf16x8*)(Ag + k0 + 32 + (size_t)16 * DMODEL);
            rb0 = *(const bf16x8*)(Bg + k0 + 32);
        }
        __syncthreads();   // LDS writes visible

        bf16x8 a[4], b[2];
#pragma unroll
        for (int t = 0; t < 4; t++)
            a[t] = *(const bf16x8*)&As[(wm * 64 + t * 16 + lo) * 32 + hi * 8];
#pragma unroll
        for (int t = 0; t < 2; t++)
            b[t] = *(const bf16x8*)&Bs[(wn * 32 + t * 16 + lo) * 32 + hi * 8];
        if (z < 2) {
#pragma unroll
            for (int tm = 0; tm < 4; tm++)
#pragma unroll
                for (int tn = 0; tn < 2; tn++)
                    acc[tm][tn] = mfma16(a[tm], b[tn], acc[tm][tn]);
        } else {
            // transposed accumulate: acc[tm][tn] = C^T tile (rows=o, cols=m)
#pragma unroll
            for (int tm = 0; tm < 4; tm++)
#pragma unroll
                for (int tn = 0; tn < 2; tn++)
                    acc[tm][tn] = mfma16(b[tn], a[tm], acc[tm][tn]);
        }
    }

    if (z < 2) {
        bf16* O = (z == 0) ? Qo : Ko;
        const float qscale = (z == 0) ? 0.18033688f : 1.0f;  // 0.125 * log2(e)
#pragma unroll
        for (int tm = 0; tm < 4; tm++)
#pragma unroll
            for (int tn = 0; tn < 2; tn++)
#pragma unroll
                for (int r = 0; r < 4; r++) {
                    int m = bm + wm * 64 + tm * 16 + hi * 4 + r;
                    int o = bn + wn * 32 + tn * 16 + lo;
                    int nidx = m >> 11, sq = m & 2047;
                    int hh = o >> 6, d = o & 63;
                    O[(((size_t)nidx * NH + hh) * SEQ + sq) * DKH + d] = (bf16)(acc[tm][tn][r] * qscale);
                }
    } else {
        // acc is C^T: row (hi*4+r) -> o (h,d); col (lo) -> m (n,sq).
#pragma unroll
        for (int tm = 0; tm < 4; tm++)
#pragma unroll
            for (int tn = 0; tn < 2; tn++)
#pragma unroll
                for (int r = 0; r < 4; r++) {
                    int o = bn + wn * 32 + tn * 16 + hi * 4 + r;
                    int m = bm + wm * 64 + tm * 16 + lo;
                    int nidx = m >> 11, sq = m & 2047;
                    int hh = o >> 6, d = o & 63;
                    Vto[(((size_t)nidx * NH + hh) * DKH + d) * SEQ + sq] = (bf16)acc[tm][tn][r];
                }
    }
}

// ---------------------------------------------------------------------------
// Kernel 3: flash attention — QBLK=128 (2 q-subtiles/wave, shared K/V
// fragment reads) + K-SPLIT x ksn, KBLK=64 (proven; 128 spills). Swapped
// QK^T + in-register softmax (cvt_pk + permlane). Grid = 32*16*ksn.
// ---------------------------------------------------------------------------
__global__ __launch_bounds__(256, 4) void attn_k(const bf16* __restrict__ Q,
                                                 const bf16* __restrict__ K,
                                                 const bf16* __restrict__ Vt,
                                                 const unsigned long long* __restrict__ mbits,
                                                 bf16* __restrict__ Op0,
                                                 bf16* __restrict__ Op1,
                                                 float* __restrict__ Lp,
                                                 int ksrange) {
    __shared__ bf16 Ks[64 * 72];
    __shared__ bf16 Vs[64 * 72];

    const int bid = blockIdx.x;
    const int xcd = bid & 7, j = bid >> 3;        // j: 0..(grid/8-1)
    const int hd = xcd * 4 + (j & 3);             // head index 0..31 (= n*16+h)
    const int qb = (j >> 2) & 15;                 // q-block 0..15 (128 rows each)
    const int ks = j >> 6;                        // k-split index (0..ksn-1)
    const int n = hd >> 4, h = hd & 15;

    const int tid = threadIdx.x, wave = tid >> 6, lane = tid & 63;
    const int lo = lane & 15, hi = lane >> 4;

    const size_t headoff = (size_t)hd * SEQ * DKH;
    const bf16* Qh = Q + headoff;
    const bf16* Kh = K + headoff;
    const bf16* Vh = Vt + headoff;   // [64][2048]

    const int qrowA = qb * 128 + wave * 16 + lo;
    const int qrowB = qrowA + 64;
    const bf16x8 aq0A = *(const bf16x8*)(Qh + (size_t)qrowA * DKH + hi * 8);
    const bf16x8 aq1A = *(const bf16x8*)(Qh + (size_t)qrowA * DKH + 32 + hi * 8);
    const bf16x8 aq0B = *(const bf16x8*)(Qh + (size_t)qrowB * DKH + hi * 8);
    const bf16x8 aq1B = *(const bf16x8*)(Qh + (size_t)qrowB * DKH + 32 + hi * 8);

    bf16x8 ones;
#pragma unroll
    for (int i = 0; i < 8; i++) ones[i] = (bf16)1.0f;

    f32x4 oaccA[4], oaccB[4];
#pragma unroll
    for (int t = 0; t < 4; t++) { oaccA[t] = 0.0f; oaccB[t] = 0.0f; }
    f32x4 laccA; laccA = 0.0f;
    f32x4 laccB; laccB = 0.0f;

    const unsigned long long* mbqA = mbits + ((size_t)n * SEQ + qrowA) * (SEQ / 64);
    const unsigned long long* mbqB = mbits + ((size_t)n * SEQ + qrowB) * (SEQ / 64);

    const int kbeg = ks * ksrange, kend = kbeg + ksrange;

    const int srow = tid >> 3, sseg = tid & 7;   // 32 rows x 64 cols per store round
    const bf16* Kg = Kh + (size_t)srow * DKH + sseg * 8;
    const bf16* Vg = Vh + (size_t)srow * SEQ + sseg * 8;

    // preload first tile of this k-range into registers
    bf16x8 rk0 = *(const bf16x8*)(Kg + (size_t)kbeg * DKH);
    bf16x8 rk1 = *(const bf16x8*)(Kg + (size_t)(kbeg + 32) * DKH);
    bf16x8 rv0 = *(const bf16x8*)(Vg + kbeg);
    bf16x8 rv1 = *(const bf16x8*)(Vg + (size_t)32 * SEQ + kbeg);
    unsigned long long wmA = mbqA[kbeg >> 6];
    unsigned long long wmB = mbqB[kbeg >> 6];
    unsigned long long wmnA = 0, wmnB = 0;

    union FragU { uint32_t u[4]; bf16x8 v; };

#pragma unroll 1
    for (int k0 = kbeg; k0 < kend; k0 += 64) {
        __syncthreads();
        *(bf16x8*)&Ks[srow * 72 + sseg * 8]        = rk0;
        *(bf16x8*)&Ks[(srow + 32) * 72 + sseg * 8] = rk1;
        *(bf16x8*)&Vs[srow * 72 + sseg * 8]        = rv0;
        *(bf16x8*)&Vs[(srow + 32) * 72 + sseg * 8] = rv1;
        if (k0 + 64 < kend) {  // prefetch next tile (overlaps compute below)
            rk0 = *(const bf16x8*)(Kg + (size_t)(k0 + 64) * DKH);
            rk1 = *(const bf16x8*)(Kg + (size_t)(k0 + 96) * DKH);
            rv0 = *(const bf16x8*)(Vg + k0 + 64);
            rv1 = *(const bf16x8*)(Vg + (size_t)32 * SEQ + k0 + 64);
            wmnA = mbqA[(k0 >> 6) + 1];
            wmnB = mbqB[(k0 >> 6) + 1];
        }
        __syncthreads();

        // S^T = K Q^T for both q-subtiles; K-fragments read ONCE, used twice.
        unsigned wloA = (unsigned)(wmA >> (hi * 4));
        unsigned whiA = (unsigned)(wmA >> (hi * 4 + 32));
        unsigned wloB = (unsigned)(wmB >> (hi * 4));
        unsigned whiB = (unsigned)(wmB >> (hi * 4 + 32));
        uint32_t pkA[4][2], pkB[4][2];
#pragma unroll
        for (int tn = 0; tn < 4; tn++) {
            const int kr = (tn * 16 + lo) * 72;
            bf16x8 b0 = *(const bf16x8*)&Ks[kr + hi * 8];
            bf16x8 b1 = *(const bf16x8*)&Ks[kr + 32 + hi * 8];
            f32x4 zA; zA = 0.0f;
            zA = mfma16(b0, aq0A, zA);
            zA = mfma16(b1, aq1A, zA);
            f32x4 zB; zB = 0.0f;
            zB = mfma16(b0, aq0B, zB);
            zB = mfma16(b1, aq1B, zB);
            unsigned wsA = ((tn < 2) ? wloA : whiA) >> ((tn & 1) * 16);
            unsigned wsB = ((tn < 2) ? wloB : whiB) >> ((tn & 1) * 16);
            float pvA[4], pvB[4];
#pragma unroll
            for (int r = 0; r < 4; r++) {
                float eA = __builtin_amdgcn_exp2f(zA[r]);
                pvA[r] = ((wsA >> r) & 1u) ? eA : 0.0f;
                float eB = __builtin_amdgcn_exp2f(zB[r]);
                pvB[r] = ((wsB >> r) & 1u) ? eB : 0.0f;
            }
            asm("v_cvt_pk_bf16_f32 %0, %1, %2" : "=v"(pkA[tn][0]) : "v"(pvA[0]), "v"(pvA[1]));
            asm("v_cvt_pk_bf16_f32 %0, %1, %2" : "=v"(pkA[tn][1]) : "v"(pvA[2]), "v"(pvA[3]));
            asm("v_cvt_pk_bf16_f32 %0, %1, %2" : "=v"(pkB[tn][0]) : "v"(pvB[0]), "v"(pvB[1]));
            asm("v_cvt_pk_bf16_f32 %0, %1, %2" : "=v"(pkB[tn][1]) : "v"(pvB[2]), "v"(pvB[3]));
        }
        wmA = wmnA;
        wmB = wmnB;

        // Redistribute across hi-groups (per sub): lane needs P[q=lo][k=..hi*8+j]
        bf16x8 ap0A, ap1A, ap0B, ap1B;
        {
            uint32_t d00 = pkA[0][0], d02 = pkA[1][0];
            PL32SWAP(d00, d02); PL16SWAP(d00, d02);
            uint32_t d01 = pkA[0][1], d03 = pkA[1][1];
            PL32SWAP(d01, d03); PL16SWAP(d01, d03);
            uint32_t d10 = pkA[2][0], d12 = pkA[3][0];
            PL32SWAP(d10, d12); PL16SWAP(d10, d12);
            uint32_t d11 = pkA[2][1], d13 = pkA[3][1];
            PL32SWAP(d11, d13); PL16SWAP(d11, d13);
            FragU f0, f1;
            f0.u[0] = d00; f0.u[1] = d01; f0.u[2] = d02; f0.u[3] = d03;
            f1.u[0] = d10; f1.u[1] = d11; f1.u[2] = d12; f1.u[3] = d13;
            ap0A = f0.v; ap1A = f1.v;
        }
        {
            uint32_t d00 = pkB[0][0], d02 = pkB[1][0];
            PL32SWAP(d00, d02); PL16SWAP(d00, d02);
            uint32_t d01 = pkB[0][1], d03 = pkB[1][1];
            PL32SWAP(d01, d03); PL16SWAP(d01, d03);
            uint32_t d10 = pkB[2][0], d12 = pkB[3][0];
            PL32SWAP(d10, d12); PL16SWAP(d10, d12);
            uint32_t d11 = pkB[2][1], d13 = pkB[3][1];
            PL32SWAP(d11, d13); PL16SWAP(d11, d13);
            FragU f0, f1;
            f0.u[0] = d00; f0.u[1] = d01; f0.u[2] = d02; f0.u[3] = d03;
            f1.u[0] = d10; f1.u[1] = d11; f1.u[2] = d12; f1.u[3] = d13;
            ap0B = f0.v; ap1B = f1.v;
        }

        // PV: V-fragments read ONCE, used for both q-subtiles.
#pragma unroll
        for (int td = 0; td < 4; td++) {
            bf16x8 b0 = *(const bf16x8*)&Vs[(td * 16 + lo) * 72 + hi * 8];
            bf16x8 b1 = *(const bf16x8*)&Vs[(td * 16 + lo) * 72 + 32 + hi * 8];
            oaccA[td] = mfma16(ap0A, b0, oaccA[td]);
            oaccA[td] = mfma16(ap1A, b1, oaccA[td]);
            oaccB[td] = mfma16(ap0B, b0, oaccB[td]);
            oaccB[td] = mfma16(ap1B, b1, oaccB[td]);
        }
        laccA = mfma16(ap0A, ones, laccA);
        laccA = mfma16(ap1A, ones, laccA);
        laccB = mfma16(ap0B, ones, laccB);
        laccB = mfma16(ap1B, ones, laccB);
    }

    // epilogue: write bf16 partial O [n,q,h*64+d] and f32 partial l [ks][n,h,q]
    bf16* Op = ks ? Op1 : Op0;
#pragma unroll
    for (int td = 0; td < 4; td++)
#pragma unroll
        for (int r = 0; r < 4; r++) {
            int qA = qb * 128 + wave * 16 + hi * 4 + r;
            int qB = qA + 64;
            int d = td * 16 + lo;
            Op[((size_t)n * SEQ + qA) * DMODEL + h * 64 + d] = (bf16)oaccA[td][r];
            Op[((size_t)n * SEQ + qB) * DMODEL + h * 64 + d] = (bf16)oaccB[td][r];
        }
    if (lo == 0) {
#pragma unroll
        for (int r = 0; r < 4; r++) {
            int qA = qb * 128 + wave * 16 + hi * 4 + r;
            int qB = qA + 64;
            size_t base = (size_t)ks * (NBATCH * NH * SEQ) + ((size_t)(n * NH + h) * SEQ);
            Lp[base + qA] = laccA[r];
            Lp[base + qB] = laccB[r];
        }
    }
}

// ---------------------------------------------------------------------------
// Kernel 4: out = ((o0+o1)/sum(l)) @ Wo^T + bo, FP32 out. 128x64 tiles
// (grid 512 = 2 blocks/CU, v14). MERGE FUSED into the A-staging (h = k0>>6
// uniform per K-step). Reg-staged T14 pipeline.
// ---------------------------------------------------------------------------
__global__ __launch_bounds__(256) void out_gemm(const bf16* __restrict__ o0,
                                                const bf16* __restrict__ o1,
                                                const float* __restrict__ lp,
                                                const bf16* __restrict__ W,
                                                const float* __restrict__ bias,
                                                float* __restrict__ Out) {
    __shared__ bf16 As[128 * 32], Bs[64 * 32];
    const int bm = blockIdx.x * 128, bn = blockIdx.y * 64;
    const int tid = threadIdx.x, wave = tid >> 6, lane = tid & 63;
    const int wm = wave >> 1, wn = wave & 1, lo = lane & 15, hi = lane >> 4;

    const int ra_row = wave * 32 + (lane >> 2);
    const int rb_row = wave * 16 + (lane >> 2);
    const int c8 = (lane & 3) * 8;
    const int m1 = bm + ra_row, m2 = m1 + 16;
    const size_t aoff1 = (size_t)m1 * DMODEL + c8;
    const size_t aoff2 = (size_t)m2 * DMODEL + c8;
    const bf16* Bg = W + (size_t)(bn + rb_row) * DMODEL + c8;
    const int NL = NBATCH * NH * SEQ;
    const int li1b = (m1 >> 11) * (NH * SEQ) + (m1 & 2047);
    const int li2b = (m2 >> 11) * (NH * SEQ) + (m2 & 2047);
    bf16* lA = &As[ra_row * 32 + c8];
    bf16* lB = &Bs[rb_row * 32 + c8];

    f32x4 acc[4][2];
#pragma unroll
    for (int i = 0; i < 4; i++)
#pragma unroll
        for (int j = 0; j < 2; j++) acc[i][j] = 0.0f;

    // prologue: prefetch k-tile 0 (h = 0)
    bf16x8 px0 = *(const bf16x8*)(o0 + aoff1);
    bf16x8 py0 = *(const bf16x8*)(o1 + aoff1);
    bf16x8 px1 = *(const bf16x8*)(o0 + aoff2);
    bf16x8 py1 = *(const bf16x8*)(o1 + aoff2);
    bf16x8 pb0 = *(const bf16x8*)(Bg);
    float pl1a = lp[li1b], pl1b = lp[NL + li1b];
    float pl2a = lp[li2b], pl2b = lp[NL + li2b];

#pragma unroll 1
    for (int k0 = 0; k0 < DMODEL; k0 += 32) {
        __syncthreads();
        float rl1 = 1.0f / (pl1a + pl1b);
        float rl2 = 1.0f / (pl2a + pl2b);
        bf16x8 wa0, wa1;
#pragma unroll
        for (int jj = 0; jj < 8; jj++) {
            wa0[jj] = (bf16)(((float)px0[jj] + (float)py0[jj]) * rl1);
            wa1[jj] = (bf16)(((float)px1[jj] + (float)py1[jj]) * rl2);
        }
        *(bf16x8*)lA         = wa0;
        *(bf16x8*)(lA + 512) = wa1;
        *(bf16x8*)lB         = pb0;
        if (k0 + 32 < DMODEL) {  // prefetch next k-tile (h = (k0+32)>>6)
            int h = (k0 + 32) >> 6;
            px0 = *(const bf16x8*)(o0 + aoff1 + k0 + 32);
            py0 = *(const bf16x8*)(o1 + aoff1 + k0 + 32);
            px1 = *(const bf16x8*)(o0 + aoff2 + k0 + 32);
            py1 = *(const bf16x8*)(o1 + aoff2 + k0 + 32);
            pb0 = *(const bf16x8*)(Bg + k0 + 32);
            int li1 = li1b + h * SEQ, li2 = li2b + h * SEQ;
            pl1a = lp[li1]; pl1b = lp[NL + li1];
            pl2a = lp[li2]; pl2b = lp[NL + li2];
        }
        __syncthreads();

        bf16x8 a[4], b[2];
#pragma unroll
        for (int t = 0; t < 4; t++)
            a[t] = *(const bf16x8*)&As[(wm * 64 + t * 16 + lo) * 32 + hi * 8];
#pragma unroll
        for (int t = 0; t < 2; t++)
            b[t] = *(const bf16x8*)&Bs[(wn * 32 + t * 16 + lo) * 32 + hi * 8];
#pragma unroll
        for (int tm = 0; tm < 4; tm++)
#pragma unroll
            for (int tn = 0; tn < 2; tn++)
                acc[tm][tn] = mfma16(a[tm], b[tn], acc[tm][tn]);
    }

#pragma unroll
    for (int tm = 0; tm < 4; tm++)
#pragma unroll
        for (int tn = 0; tn < 2; tn++) {
            int o = bn + wn * 32 + tn * 16 + lo;
            float bv = bias[o];
#pragma unroll
            for (int r = 0; r < 4; r++) {
                int m = bm + wm * 64 + tm * 16 + hi * 4 + r;
                Out[(size_t)m * DMODEL + o] = acc[tm][tn][r] + bv;
            }
        }
}

// ---------------------------------------------------------------------------
extern "C" void kernel_launch(void* const* d_in, const int* in_sizes, int n_in,
                              void* d_out, int out_size, void* d_ws, size_t ws_size,
                              hipStream_t stream) {
    const float* value = (const float*)d_in[0];
    const float* key   = (const float*)d_in[1];
    const float* query = (const float*)d_in[2];
    const int*   mask  = (const int*)d_in[3];
    const float* Wq    = (const float*)d_in[4];
    const float* Wk    = (const float*)d_in[5];
    const float* Wv    = (const float*)d_in[6];
    const float* Wo    = (const float*)d_in[7];
    const float* bo    = (const float*)d_in[8];
    float* out = (float*)d_out;

    char* ws = (char*)d_ws;
    bf16* Qws = (bf16*)(ws);                         // 8 MB [n,h,s,64]
    bf16* Kws = (bf16*)(ws + (8u  << 20));           // 8 MB [n,h,s,64]
    bf16* Vt  = (bf16*)(ws + (16u << 20));           // 8 MB [n,h,64,s]
    bf16* Xqb = (bf16*)(ws + (24u << 20));           // 8 MB; after qkv: o_part0
    bf16* Xkb = (bf16*)(ws + (32u << 20));           // 8 MB; after qkv: o_part1
    bf16* Xvb = (bf16*)(ws + (40u << 20));           // 8 MB
    bf16* Wqb = (bf16*)(ws + (48u << 20));           // 2 MB; after qkv: l_part (512KB)
    bf16* Wkb = (bf16*)(ws + (50u << 20));           // 2 MB
    bf16* Wvb = (bf16*)(ws + (52u << 20));           // 2 MB
    bf16* Wob = (bf16*)(ws + (54u << 20));           // 2 MB (live until out_gemm)
    unsigned long long* mbits = (unsigned long long*)(ws + (56u << 20));  // 1 MB
    bf16*  Op0 = Xqb;
    bf16*  Op1 = Xkb;
    float* Lp  = (float*)Wqb;

    // K-SPLIT x2 (x4 measured NULL in R4 — attn is not TLP-bound)
    const int  ksn     = 2;
    const int  ksrange = SEQ / ksn;
    const int  attn_grid = 32 * 16 * ksn;            // heads * q-blocks * k-splits

    cvt_all_k<<<dim3(1024, 8), 256, 0, stream>>>(query, key, value, Wq, Wk, Wv, Wo, mask,
                                                 Xqb, Xkb, Xvb, Wqb, Wkb, Wvb, Wob, mbits);
    qkv_gemm<<<dim3(32, 16, 3), 256, 0, stream>>>(Xqb, Xkb, Xvb, Wqb, Wkb, Wvb, Qws, Kws, Vt);
    attn_k<<<attn_grid, 256, 0, stream>>>(Qws, Kws, Vt, mbits, Op0, Op1, Lp, ksrange);
    out_gemm<<<dim3(32, 16), 256, 0, stream>>>(Op0, Op1, Lp, Wob, bo, out);
}

// Round 12
// 272.786 us; speedup vs baseline: 1.1437x; 1.0078x over previous
//
#include <hip/hip_runtime.h>
#include <hip/hip_bf16.h>
#include <stdint.h>

// All FLOAT32 I/O. bf16 compute via convert pre-pass.
// GEMMs: T14 reg-staged pipeline, 128x64 tiles. attn: flash, K-SPLIT x2,
// fixed-base softmax, QBLK=128, KBLK=128 (v15: retry of R8's ILP structure
// with launch_bounds(256,3) -> VGPR cap 170; R8's failure was a SPILL at
// cap 128, not the ILP concept. Tripwire: WRITE_SIZE must stay ~16.9MB).
// merge fused into out_gemm.
// History: v8/v13 FAILED (reg spills; tripwire=WRITE_SIZE); v10 NULL
// (ksplit x4); v12 FAILED (GLDS16 dbuf drains in-iter); v14 NULL (GEMM
// retile TLP — per-iter serial chains, not wave supply, limit these loops).
// R11: container-acquisition infra failure (like R9); v15 re-audited
// (LDS bounds, mask indices, reg budget) and resubmitted unchanged.
#define SEQ     2048
#define NBATCH  2
#define DMODEL  1024
#define NH      16
#define DKH     64

typedef __bf16 bf16;
typedef __attribute__((ext_vector_type(8))) __bf16 bf16x8;
typedef __attribute__((ext_vector_type(4))) __bf16 bf16x4;
typedef __attribute__((ext_vector_type(4))) float  f32x4;

static __device__ __forceinline__ f32x4 mfma16(bf16x8 a, bf16x8 b, f32x4 c) {
    return __builtin_amdgcn_mfma_f32_16x16x32_bf16(a, b, c, 0, 0, 0);
}

// in-place cross-lane row swaps (gfx950)
#define PL32SWAP(a, b) asm("v_permlane32_swap_b32 %0, %1" : "+v"(a), "+v"(b))
#define PL16SWAP(a, b) asm("v_permlane16_swap_b32 %0, %1" : "+v"(a), "+v"(b))

// ---------------------------------------------------------------------------
// Kernel 0: f32 -> bf16 convert for X (q,k,v) and W (wq,wk,wv,wo); y=7 packs
// mask [n,1,s,s] int32 -> bitmask uint64 [n*s, s/64].
// ---------------------------------------------------------------------------
__global__ __launch_bounds__(256) void cvt_all_k(const float* __restrict__ q,
                                                 const float* __restrict__ k,
                                                 const float* __restrict__ v,
                                                 const float* __restrict__ wq,
                                                 const float* __restrict__ wk,
                                                 const float* __restrict__ wv,
                                                 const float* __restrict__ wo,
                                                 const int* __restrict__ mask,
                                                 bf16* __restrict__ qb, bf16* __restrict__ kb,
                                                 bf16* __restrict__ vb, bf16* __restrict__ wqb,
                                                 bf16* __restrict__ wkb, bf16* __restrict__ wvb,
                                                 bf16* __restrict__ wob,
                                                 unsigned long long* __restrict__ mbits) {
    if (blockIdx.y == 7) {  // mask pack
        const int nwords = NBATCH * SEQ * (SEQ / 64);
        int wave  = (blockIdx.x * blockDim.x + threadIdx.x) >> 6;
        int lane  = threadIdx.x & 63;
        int nwtot = (gridDim.x * blockDim.x) >> 6;
        for (int w = wave; w < nwords; w += nwtot) {
            int m = mask[(size_t)w * 64 + lane];
            unsigned long long b = __ballot(m != 0);
            if (lane == 0) mbits[w] = b;
        }
        return;
    }
    const float* src; bf16* dst; int n4;
    const int NX4 = (NBATCH * SEQ * DMODEL) / 4, NW4 = (DMODEL * DMODEL) / 4;
    switch (blockIdx.y) {
        case 0: src = q;  dst = qb;  n4 = NX4; break;
        case 1: src = k;  dst = kb;  n4 = NX4; break;
        case 2: src = v;  dst = vb;  n4 = NX4; break;
        case 3: src = wq; dst = wqb; n4 = NW4; break;
        case 4: src = wk; dst = wkb; n4 = NW4; break;
        case 5: src = wv; dst = wvb; n4 = NW4; break;
        default: src = wo; dst = wob; n4 = NW4; break;
    }
    int stride = gridDim.x * blockDim.x;
    for (int i = blockIdx.x * blockDim.x + threadIdx.x; i < n4; i += stride) {
        f32x4 f = ((const f32x4*)src)[i];
        bf16x4 o;
#pragma unroll
        for (int j = 0; j < 4; j++) o[j] = (bf16)f[j];
        ((bf16x4*)dst)[i] = o;
    }
}

// ---------------------------------------------------------------------------
// Kernel 2: QKV projection. 128x64 tiles, reg-staged T14 pipeline.
// Grid (32,16,3) = 1536 blocks. z=0:Q (pre-scaled) z=1:K -> [n,h,s,64];
// z=2:V -> [n,h,64,s] via transposed accumulate (operand swap).
// ---------------------------------------------------------------------------
__global__ __launch_bounds__(256) void qkv_gemm(const bf16* __restrict__ Xq,
                                                const bf16* __restrict__ Xk,
                                                const bf16* __restrict__ Xv,
                                                const bf16* __restrict__ Wq,
                                                const bf16* __restrict__ Wk,
                                                const bf16* __restrict__ Wv,
                                                bf16* __restrict__ Qo,
                                                bf16* __restrict__ Ko,
                                                bf16* __restrict__ Vto) {
    __shared__ bf16 As[128 * 32], Bs[64 * 32];
    const int z = blockIdx.z;
    const bf16* A = (z == 0) ? Xq : (z == 1) ? Xk : Xv;
    const bf16* W = (z == 0) ? Wq : (z == 1) ? Wk : Wv;
    const int bm = blockIdx.x * 128, bn = blockIdx.y * 64;
    const int tid = threadIdx.x, wave = tid >> 6, lane = tid & 63;
    const int wm = wave >> 1, wn = wave & 1, lo = lane & 15, hi = lane >> 4;

    const int ra_row = wave * 32 + (lane >> 2);   // A: 4 waves x 32 = 128 rows
    const int rb_row = wave * 16 + (lane >> 2);   // B: 4 waves x 16 = 64 rows
    const int c8 = (lane & 3) * 8;
    const bf16* Ag = A + (size_t)(bm + ra_row) * DMODEL + c8;
    const bf16* Bg = W + (size_t)(bn + rb_row) * DMODEL + c8;
    bf16* lA = &As[ra_row * 32 + c8];
    bf16* lB = &Bs[rb_row * 32 + c8];

    f32x4 acc[4][2];
#pragma unroll
    for (int i = 0; i < 4; i++)
#pragma unroll
        for (int j = 0; j < 2; j++) acc[i][j] = 0.0f;

    // prologue: prefetch k-tile 0 into registers
    bf16x8 ra0 = *(const bf16x8*)(Ag);
    bf16x8 ra1 = *(const bf16x8*)(Ag + (size_t)16 * DMODEL);
    bf16x8 rb0 = *(const bf16x8*)(Bg);

#pragma unroll 1
    for (int k0 = 0; k0 < DMODEL; k0 += 32) {
        __syncthreads();   // all waves done reading LDS from previous iter
        *(bf16x8*)lA         = ra0;
        *(bf16x8*)(lA + 512) = ra1;   // +16 rows
        *(bf16x8*)lB         = rb0;
        if (k0 + 32 < DMODEL) {  // issue next-tile loads; consumed next iter
            ra0 = *(const bf16x8*)(Ag + k0 + 32);
            ra1 = *(const bf16x8*)(Ag + k0 + 32 + (size_t)16 * DMODEL);
            rb0 = *(const bf16x8*)(Bg + k0 + 32);
        }
        __syncthreads();   // LDS writes visible

        bf16x8 a[4], b[2];
#pragma unroll
        for (int t = 0; t < 4; t++)
            a[t] = *(const bf16x8*)&As[(wm * 64 + t * 16 + lo) * 32 + hi * 8];
#pragma unroll
        for (int t = 0; t < 2; t++)
            b[t] = *(const bf16x8*)&Bs[(wn * 32 + t * 16 + lo) * 32 + hi * 8];
        if (z < 2) {
#pragma unroll
            for (int tm = 0; tm < 4; tm++)
#pragma unroll
                for (int tn = 0; tn < 2; tn++)
                    acc[tm][tn] = mfma16(a[tm], b[tn], acc[tm][tn]);
        } else {
            // transposed accumulate: acc[tm][tn] = C^T tile (rows=o, cols=m)
#pragma unroll
            for (int tm = 0; tm < 4; tm++)
#pragma unroll
                for (int tn = 0; tn < 2; tn++)
                    acc[tm][tn] = mfma16(b[tn], a[tm], acc[tm][tn]);
        }
    }

    if (z < 2) {
        bf16* O = (z == 0) ? Qo : Ko;
        const float qscale = (z == 0) ? 0.18033688f : 1.0f;  // 0.125 * log2(e)
#pragma unroll
        for (int tm = 0; tm < 4; tm++)
#pragma unroll
            for (int tn = 0; tn < 2; tn++)
#pragma unroll
                for (int r = 0; r < 4; r++) {
                    int m = bm + wm * 64 + tm * 16 + hi * 4 + r;
                    int o = bn + wn * 32 + tn * 16 + lo;
                    int nidx = m >> 11, sq = m & 2047;
                    int hh = o >> 6, d = o & 63;
                    O[(((size_t)nidx * NH + hh) * SEQ + sq) * DKH + d] = (bf16)(acc[tm][tn][r] * qscale);
                }
    } else {
        // acc is C^T: row (hi*4+r) -> o (h,d); col (lo) -> m (n,sq).
#pragma unroll
        for (int tm = 0; tm < 4; tm++)
#pragma unroll
            for (int tn = 0; tn < 2; tn++)
#pragma unroll
                for (int r = 0; r < 4; r++) {
                    int o = bn + wn * 32 + tn * 16 + hi * 4 + r;
                    int m = bm + wm * 64 + tm * 16 + lo;
                    int nidx = m >> 11, sq = m & 2047;
                    int hh = o >> 6, d = o & 63;
                    Vto[(((size_t)nidx * NH + hh) * DKH + d) * SEQ + sq] = (bf16)acc[tm][tn][r];
                }
    }
}

// ---------------------------------------------------------------------------
// Kernel 3: flash attention v15 — QBLK=128 + KBLK=128: TWO independent 64-k
// S->softmax->PV chains per barrier pair (ILP inside the barrier section;
// TLP proven null R4/R10). launch_bounds(256,3): VGPR cap 170 so the ~148
// peak fits WITHOUT spill (R8's failure mode at cap 128). Swapped QK^T +
// in-register softmax. K-SPLIT x ksn. LDS Ks[128][72]+Vs[64][136]=35.8KB.
// ---------------------------------------------------------------------------
__global__ __launch_bounds__(256, 3) void attn_k(const bf16* __restrict__ Q,
                                                 const bf16* __restrict__ K,
                                                 const bf16* __restrict__ Vt,
                                                 const unsigned long long* __restrict__ mbits,
                                                 bf16* __restrict__ Op0,
                                                 bf16* __restrict__ Op1,
                                                 float* __restrict__ Lp,
                                                 int ksrange) {
    __shared__ bf16 Ks[128 * 72];
    __shared__ bf16 Vs[64 * 136];

    const int bid = blockIdx.x;
    const int xcd = bid & 7, j = bid >> 3;        // j: 0..(grid/8-1)
    const int hd = xcd * 4 + (j & 3);             // head index 0..31 (= n*16+h)
    const int qb = (j >> 2) & 15;                 // q-block 0..15 (128 rows each)
    const int ks = j >> 6;                        // k-split index (0..ksn-1)
    const int n = hd >> 4, h = hd & 15;

    const int tid = threadIdx.x, wave = tid >> 6, lane = tid & 63;
    const int lo = lane & 15, hi = lane >> 4;

    const size_t headoff = (size_t)hd * SEQ * DKH;
    const bf16* Qh = Q + headoff;
    const bf16* Kh = K + headoff;
    const bf16* Vh = Vt + headoff;   // [64][2048]

    const int qrowA = qb * 128 + wave * 16 + lo;
    const int qrowB = qrowA + 64;
    const bf16x8 aq0A = *(const bf16x8*)(Qh + (size_t)qrowA * DKH + hi * 8);
    const bf16x8 aq1A = *(const bf16x8*)(Qh + (size_t)qrowA * DKH + 32 + hi * 8);
    const bf16x8 aq0B = *(const bf16x8*)(Qh + (size_t)qrowB * DKH + hi * 8);
    const bf16x8 aq1B = *(const bf16x8*)(Qh + (size_t)qrowB * DKH + 32 + hi * 8);

    bf16x8 ones;
#pragma unroll
    for (int i = 0; i < 8; i++) ones[i] = (bf16)1.0f;

    f32x4 oaccA[4], oaccB[4];
#pragma unroll
    for (int t = 0; t < 4; t++) { oaccA[t] = 0.0f; oaccB[t] = 0.0f; }
    f32x4 laccA; laccA = 0.0f;
    f32x4 laccB; laccB = 0.0f;

    const unsigned long long* mbqA = mbits + ((size_t)n * SEQ + qrowA) * (SEQ / 64);
    const unsigned long long* mbqB = mbits + ((size_t)n * SEQ + qrowB) * (SEQ / 64);

    const int kbeg = ks * ksrange, kend = kbeg + ksrange;

    const int srow = tid >> 3, sseg = tid & 7;   // 32 rows x 64 cols per store round
    const bf16* Kg = Kh + (size_t)srow * DKH + sseg * 8;
    const bf16* Vg = Vh + (size_t)srow * SEQ + sseg * 8;

    // preload first 128-k tile of this k-range into registers
    bf16x8 rk0 = *(const bf16x8*)(Kg + (size_t)(kbeg)      * DKH);
    bf16x8 rk1 = *(const bf16x8*)(Kg + (size_t)(kbeg + 32) * DKH);
    bf16x8 rk2 = *(const bf16x8*)(Kg + (size_t)(kbeg + 64) * DKH);
    bf16x8 rk3 = *(const bf16x8*)(Kg + (size_t)(kbeg + 96) * DKH);
    bf16x8 rv0 = *(const bf16x8*)(Vg + kbeg);
    bf16x8 rv1 = *(const bf16x8*)(Vg + (size_t)32 * SEQ + kbeg);
    bf16x8 rv2 = *(const bf16x8*)(Vg + kbeg + 64);
    bf16x8 rv3 = *(const bf16x8*)(Vg + (size_t)32 * SEQ + kbeg + 64);
    unsigned long long wmA0 = mbqA[(kbeg >> 6)], wmA1 = mbqA[(kbeg >> 6) + 1];
    unsigned long long wmB0 = mbqB[(kbeg >> 6)], wmB1 = mbqB[(kbeg >> 6) + 1];
    unsigned long long wmnA0 = 0, wmnA1 = 0, wmnB0 = 0, wmnB1 = 0;

    union FragU { uint32_t u[4]; bf16x8 v; };

    // one 64-k tile: S^T (both q-subtiles) -> masked exp2 -> pack/permlane ->
    // PV accumulate. koff selects tile row/col base inside Ks/Vs.
    auto tile = [&](int koff, unsigned long long wmA, unsigned long long wmB) {
        unsigned wloA = (unsigned)(wmA >> (hi * 4));
        unsigned whiA = (unsigned)(wmA >> (hi * 4 + 32));
        unsigned wloB = (unsigned)(wmB >> (hi * 4));
        unsigned whiB = (unsigned)(wmB >> (hi * 4 + 32));
        uint32_t pkA[4][2], pkB[4][2];
#pragma unroll
        for (int tn = 0; tn < 4; tn++) {
            const int kr = (koff + tn * 16 + lo) * 72;
            bf16x8 b0 = *(const bf16x8*)&Ks[kr + hi * 8];
            bf16x8 b1 = *(const bf16x8*)&Ks[kr + 32 + hi * 8];
            f32x4 zA; zA = 0.0f;
            zA = mfma16(b0, aq0A, zA);
            zA = mfma16(b1, aq1A, zA);
            f32x4 zB; zB = 0.0f;
            zB = mfma16(b0, aq0B, zB);
            zB = mfma16(b1, aq1B, zB);
            unsigned wsA = ((tn < 2) ? wloA : whiA) >> ((tn & 1) * 16);
            unsigned wsB = ((tn < 2) ? wloB : whiB) >> ((tn & 1) * 16);
            float pvA[4], pvB[4];
#pragma unroll
            for (int r = 0; r < 4; r++) {
                float eA = __builtin_amdgcn_exp2f(zA[r]);
                pvA[r] = ((wsA >> r) & 1u) ? eA : 0.0f;
                float eB = __builtin_amdgcn_exp2f(zB[r]);
                pvB[r] = ((wsB >> r) & 1u) ? eB : 0.0f;
            }
            asm("v_cvt_pk_bf16_f32 %0, %1, %2" : "=v"(pkA[tn][0]) : "v"(pvA[0]), "v"(pvA[1]));
            asm("v_cvt_pk_bf16_f32 %0, %1, %2" : "=v"(pkA[tn][1]) : "v"(pvA[2]), "v"(pvA[3]));
            asm("v_cvt_pk_bf16_f32 %0, %1, %2" : "=v"(pkB[tn][0]) : "v"(pvB[0]), "v"(pvB[1]));
            asm("v_cvt_pk_bf16_f32 %0, %1, %2" : "=v"(pkB[tn][1]) : "v"(pvB[2]), "v"(pvB[3]));
        }

        bf16x8 ap0A, ap1A, ap0B, ap1B;
        {
            uint32_t d00 = pkA[0][0], d02 = pkA[1][0];
            PL32SWAP(d00, d02); PL16SWAP(d00, d02);
            uint32_t d01 = pkA[0][1], d03 = pkA[1][1];
            PL32SWAP(d01, d03); PL16SWAP(d01, d03);
            uint32_t d10 = pkA[2][0], d12 = pkA[3][0];
            PL32SWAP(d10, d12); PL16SWAP(d10, d12);
            uint32_t d11 = pkA[2][1], d13 = pkA[3][1];
            PL32SWAP(d11, d13); PL16SWAP(d11, d13);
            FragU f0, f1;
            f0.u[0] = d00; f0.u[1] = d01; f0.u[2] = d02; f0.u[3] = d03;
            f1.u[0] = d10; f1.u[1] = d11; f1.u[2] = d12; f1.u[3] = d13;
            ap0A = f0.v; ap1A = f1.v;
        }
        {
            uint32_t d00 = pkB[0][0], d02 = pkB[1][0];
            PL32SWAP(d00, d02); PL16SWAP(d00, d02);
            uint32_t d01 = pkB[0][1], d03 = pkB[1][1];
            PL32SWAP(d01, d03); PL16SWAP(d01, d03);
            uint32_t d10 = pkB[2][0], d12 = pkB[3][0];
            PL32SWAP(d10, d12); PL16SWAP(d10, d12);
            uint32_t d11 = pkB[2][1], d13 = pkB[3][1];
            PL32SWAP(d11, d13); PL16SWAP(d11, d13);
            FragU f0, f1;
            f0.u[0] = d00; f0.u[1] = d01; f0.u[2] = d02; f0.u[3] = d03;
            f1.u[0] = d10; f1.u[1] = d11; f1.u[2] = d12; f1.u[3] = d13;
            ap0B = f0.v; ap1B = f1.v;
        }

#pragma unroll
        for (int td = 0; td < 4; td++) {
            bf16x8 b0 = *(const bf16x8*)&Vs[(td * 16 + lo) * 136 + koff + hi * 8];
            bf16x8 b1 = *(const bf16x8*)&Vs[(td * 16 + lo) * 136 + koff + 32 + hi * 8];
            oaccA[td] = mfma16(ap0A, b0, oaccA[td]);
            oaccA[td] = mfma16(ap1A, b1, oaccA[td]);
            oaccB[td] = mfma16(ap0B, b0, oaccB[td]);
            oaccB[td] = mfma16(ap1B, b1, oaccB[td]);
        }
        laccA = mfma16(ap0A, ones, laccA);
        laccA = mfma16(ap1A, ones, laccA);
        laccB = mfma16(ap0B, ones, laccB);
        laccB = mfma16(ap1B, ones, laccB);
    };

#pragma unroll 1
    for (int k0 = kbeg; k0 < kend; k0 += 128) {
        __syncthreads();
        *(bf16x8*)&Ks[(srow)      * 72 + sseg * 8] = rk0;
        *(bf16x8*)&Ks[(srow + 32) * 72 + sseg * 8] = rk1;
        *(bf16x8*)&Ks[(srow + 64) * 72 + sseg * 8] = rk2;
        *(bf16x8*)&Ks[(srow + 96) * 72 + sseg * 8] = rk3;
        *(bf16x8*)&Vs[(srow)      * 136 + sseg * 8]      = rv0;
        *(bf16x8*)&Vs[(srow + 32) * 136 + sseg * 8]      = rv1;
        *(bf16x8*)&Vs[(srow)      * 136 + 64 + sseg * 8] = rv2;
        *(bf16x8*)&Vs[(srow + 32) * 136 + 64 + sseg * 8] = rv3;
        if (k0 + 128 < kend) {  // prefetch next 128-k tile (covered by compute)
            rk0 = *(const bf16x8*)(Kg + (size_t)(k0 + 128) * DKH);
            rk1 = *(const bf16x8*)(Kg + (size_t)(k0 + 160) * DKH);
            rk2 = *(const bf16x8*)(Kg + (size_t)(k0 + 192) * DKH);
            rk3 = *(const bf16x8*)(Kg + (size_t)(k0 + 224) * DKH);
            rv0 = *(const bf16x8*)(Vg + k0 + 128);
            rv1 = *(const bf16x8*)(Vg + (size_t)32 * SEQ + k0 + 128);
            rv2 = *(const bf16x8*)(Vg + k0 + 192);
            rv3 = *(const bf16x8*)(Vg + (size_t)32 * SEQ + k0 + 192);
            wmnA0 = mbqA[(k0 >> 6) + 2]; wmnA1 = mbqA[(k0 >> 6) + 3];
            wmnB0 = mbqB[(k0 >> 6) + 2]; wmnB1 = mbqB[(k0 >> 6) + 3];
        }
        __syncthreads();

        tile(0,  wmA0, wmB0);   // two independent chains inside one barrier
        tile(64, wmA1, wmB1);   // section: scheduler overlaps S1 with SM0

        wmA0 = wmnA0; wmA1 = wmnA1;
        wmB0 = wmnB0; wmB1 = wmnB1;
    }

    // epilogue: write bf16 partial O [n,q,h*64+d] and f32 partial l [ks][n,h,q]
    bf16* Op = ks ? Op1 : Op0;
#pragma unroll
    for (int td = 0; td < 4; td++)
#pragma unroll
        for (int r = 0; r < 4; r++) {
            int qA = qb * 128 + wave * 16 + hi * 4 + r;
            int qB = qA + 64;
            int d = td * 16 + lo;
            Op[((size_t)n * SEQ + qA) * DMODEL + h * 64 + d] = (bf16)oaccA[td][r];
            Op[((size_t)n * SEQ + qB) * DMODEL + h * 64 + d] = (bf16)oaccB[td][r];
        }
    if (lo == 0) {
#pragma unroll
        for (int r = 0; r < 4; r++) {
            int qA = qb * 128 + wave * 16 + hi * 4 + r;
            int qB = qA + 64;
            size_t base = (size_t)ks * (NBATCH * NH * SEQ) + ((size_t)(n * NH + h) * SEQ);
            Lp[base + qA] = laccA[r];
            Lp[base + qB] = laccB[r];
        }
    }
}

// ---------------------------------------------------------------------------
// Kernel 4: out = ((o0+o1)/sum(l)) @ Wo^T + bo, FP32 out. 128x64 tiles
// (grid 512). MERGE FUSED into the A-staging (h = k0>>6 uniform per
// K-step). Reg-staged T14 pipeline.
// ---------------------------------------------------------------------------
__global__ __launch_bounds__(256) void out_gemm(const bf16* __restrict__ o0,
                                                const bf16* __restrict__ o1,
                                                const float* __restrict__ lp,
                                                const bf16* __restrict__ W,
                                                const float* __restrict__ bias,
                                                float* __restrict__ Out) {
    __shared__ bf16 As[128 * 32], Bs[64 * 32];
    const int bm = blockIdx.x * 128, bn = blockIdx.y * 64;
    const int tid = threadIdx.x, wave = tid >> 6, lane = tid & 63;
    const int wm = wave >> 1, wn = wave & 1, lo = lane & 15, hi = lane >> 4;

    const int ra_row = wave * 32 + (lane >> 2);
    const int rb_row = wave * 16 + (lane >> 2);
    const int c8 = (lane & 3) * 8;
    const int m1 = bm + ra_row, m2 = m1 + 16;
    const size_t aoff1 = (size_t)m1 * DMODEL + c8;
    const size_t aoff2 = (size_t)m2 * DMODEL + c8;
    const bf16* Bg = W + (size_t)(bn + rb_row) * DMODEL + c8;
    const int NL = NBATCH * NH * SEQ;
    const int li1b = (m1 >> 11) * (NH * SEQ) + (m1 & 2047);
    const int li2b = (m2 >> 11) * (NH * SEQ) + (m2 & 2047);
    bf16* lA = &As[ra_row * 32 + c8];
    bf16* lB = &Bs[rb_row * 32 + c8];

    f32x4 acc[4][2];
#pragma unroll
    for (int i = 0; i < 4; i++)
#pragma unroll
        for (int j = 0; j < 2; j++) acc[i][j] = 0.0f;

    // prologue: prefetch k-tile 0 (h = 0)
    bf16x8 px0 = *(const bf16x8*)(o0 + aoff1);
    bf16x8 py0 = *(const bf16x8*)(o1 + aoff1);
    bf16x8 px1 = *(const bf16x8*)(o0 + aoff2);
    bf16x8 py1 = *(const bf16x8*)(o1 + aoff2);
    bf16x8 pb0 = *(const bf16x8*)(Bg);
    float pl1a = lp[li1b], pl1b = lp[NL + li1b];
    float pl2a = lp[li2b], pl2b = lp[NL + li2b];

#pragma unroll 1
    for (int k0 = 0; k0 < DMODEL; k0 += 32) {
        __syncthreads();
        float rl1 = 1.0f / (pl1a + pl1b);
        float rl2 = 1.0f / (pl2a + pl2b);
        bf16x8 wa0, wa1;
#pragma unroll
        for (int jj = 0; jj < 8; jj++) {
            wa0[jj] = (bf16)(((float)px0[jj] + (float)py0[jj]) * rl1);
            wa1[jj] = (bf16)(((float)px1[jj] + (float)py1[jj]) * rl2);
        }
        *(bf16x8*)lA         = wa0;
        *(bf16x8*)(lA + 512) = wa1;
        *(bf16x8*)lB         = pb0;
        if (k0 + 32 < DMODEL) {  // prefetch next k-tile (h = (k0+32)>>6)
            int h = (k0 + 32) >> 6;
            px0 = *(const bf16x8*)(o0 + aoff1 + k0 + 32);
            py0 = *(const bf16x8*)(o1 + aoff1 + k0 + 32);
            px1 = *(const bf16x8*)(o0 + aoff2 + k0 + 32);
            py1 = *(const bf16x8*)(o1 + aoff2 + k0 + 32);
            pb0 = *(const bf16x8*)(Bg + k0 + 32);
            int li1 = li1b + h * SEQ, li2 = li2b + h * SEQ;
            pl1a = lp[li1]; pl1b = lp[NL + li1];
            pl2a = lp[li2]; pl2b = lp[NL + li2];
        }
        __syncthreads();

        bf16x8 a[4], b[2];
#pragma unroll
        for (int t = 0; t < 4; t++)
            a[t] = *(const bf16x8*)&As[(wm * 64 + t * 16 + lo) * 32 + hi * 8];
#pragma unroll
        for (int t = 0; t < 2; t++)
            b[t] = *(const bf16x8*)&Bs[(wn * 32 + t * 16 + lo) * 32 + hi * 8];
#pragma unroll
        for (int tm = 0; tm < 4; tm++)
#pragma unroll
            for (int tn = 0; tn < 2; tn++)
                acc[tm][tn] = mfma16(a[tm], b[tn], acc[tm][tn]);
    }

#pragma unroll
    for (int tm = 0; tm < 4; tm++)
#pragma unroll
        for (int tn = 0; tn < 2; tn++) {
            int o = bn + wn * 32 + tn * 16 + lo;
            float bv = bias[o];
#pragma unroll
            for (int r = 0; r < 4; r++) {
                int m = bm + wm * 64 + tm * 16 + hi * 4 + r;
                Out[(size_t)m * DMODEL + o] = acc[tm][tn][r] + bv;
            }
        }
}

// ---------------------------------------------------------------------------
extern "C" void kernel_launch(void* const* d_in, const int* in_sizes, int n_in,
                              void* d_out, int out_size, void* d_ws, size_t ws_size,
                              hipStream_t stream) {
    const float* value = (const float*)d_in[0];
    const float* key   = (const float*)d_in[1];
    const float* query = (const float*)d_in[2];
    const int*   mask  = (const int*)d_in[3];
    const float* Wq    = (const float*)d_in[4];
    const float* Wk    = (const float*)d_in[5];
    const float* Wv    = (const float*)d_in[6];
    const float* Wo    = (const float*)d_in[7];
    const float* bo    = (const float*)d_in[8];
    float* out = (float*)d_out;

    char* ws = (char*)d_ws;
    bf16* Qws = (bf16*)(ws);                         // 8 MB [n,h,s,64]
    bf16* Kws = (bf16*)(ws + (8u  << 20));           // 8 MB [n,h,s,64]
    bf16* Vt  = (bf16*)(ws + (16u << 20));           // 8 MB [n,h,64,s]
    bf16* Xqb = (bf16*)(ws + (24u << 20));           // 8 MB; after qkv: o_part0
    bf16* Xkb = (bf16*)(ws + (32u << 20));           // 8 MB; after qkv: o_part1
    bf16* Xvb = (bf16*)(ws + (40u << 20));           // 8 MB
    bf16* Wqb = (bf16*)(ws + (48u << 20));           // 2 MB; after qkv: l_part (512KB)
    bf16* Wkb = (bf16*)(ws + (50u << 20));           // 2 MB
    bf16* Wvb = (bf16*)(ws + (52u << 20));           // 2 MB
    bf16* Wob = (bf16*)(ws + (54u << 20));           // 2 MB (live until out_gemm)
    unsigned long long* mbits = (unsigned long long*)(ws + (56u << 20));  // 1 MB
    bf16*  Op0 = Xqb;
    bf16*  Op1 = Xkb;
    float* Lp  = (float*)Wqb;

    // K-SPLIT x2 (x4 measured NULL in R4 — attn is not TLP-bound)
    const int  ksn     = 2;
    const int  ksrange = SEQ / ksn;
    const int  attn_grid = 32 * 16 * ksn;            // heads * q-blocks * k-splits

    cvt_all_k<<<dim3(1024, 8), 256, 0, stream>>>(query, key, value, Wq, Wk, Wv, Wo, mask,
                                                 Xqb, Xkb, Xvb, Wqb, Wkb, Wvb, Wob, mbits);
    qkv_gemm<<<dim3(32, 16, 3), 256, 0, stream>>>(Xqb, Xkb, Xvb, Wqb, Wkb, Wvb, Qws, Kws, Vt);
    attn_k<<<attn_grid, 256, 0, stream>>>(Qws, Kws, Vt, mbits, Op0, Op1, Lp, ksrange);
    out_gemm<<<dim3(32, 16), 256, 0, stream>>>(Op0, Op1, Lp, Wob, bo, out);
}

// Round 13
// 264.676 us; speedup vs baseline: 1.1788x; 1.0306x over previous
//
#include <hip/hip_runtime.h>
#include <hip/hip_bf16.h>
#include <stdint.h>

// All FLOAT32 I/O. bf16 compute via convert pre-pass.
// GEMMs v16: T14 reg-staged pipeline, 128x64 tiles, BK=64 (halved barriers,
// doubled prefetch-coverage window vs BK=32), LDS rows padded to 72
// (64-wide rows would be 128B stride = all-banks-0 pathological conflict).
// attn: v15 flash (QBLK=128, KBLK=128, K-SPLIT x2, fixed-base softmax,
// in-register softmax) — measured at its structural floor ~60us (TLP null
// R4/R10, ILP null R12). merge fused into out_gemm.
// History: v8/v13 FAILED (reg spills; tripwire=WRITE_SIZE); v10 NULL
// (ksplit x4); v12 FAILED (GLDS16 dbuf drains in-iter); v14 NULL (GEMM
// retile TLP); v15 NULL on attn but clean (kept).
#define SEQ     2048
#define NBATCH  2
#define DMODEL  1024
#define NH      16
#define DKH     64

typedef __bf16 bf16;
typedef __attribute__((ext_vector_type(8))) __bf16 bf16x8;
typedef __attribute__((ext_vector_type(4))) __bf16 bf16x4;
typedef __attribute__((ext_vector_type(4))) float  f32x4;

static __device__ __forceinline__ f32x4 mfma16(bf16x8 a, bf16x8 b, f32x4 c) {
    return __builtin_amdgcn_mfma_f32_16x16x32_bf16(a, b, c, 0, 0, 0);
}

// in-place cross-lane row swaps (gfx950)
#define PL32SWAP(a, b) asm("v_permlane32_swap_b32 %0, %1" : "+v"(a), "+v"(b))
#define PL16SWAP(a, b) asm("v_permlane16_swap_b32 %0, %1" : "+v"(a), "+v"(b))

// ---------------------------------------------------------------------------
// Kernel 0: f32 -> bf16 convert for X (q,k,v) and W (wq,wk,wv,wo); y=7 packs
// mask [n,1,s,s] int32 -> bitmask uint64 [n*s, s/64].
// ---------------------------------------------------------------------------
__global__ __launch_bounds__(256) void cvt_all_k(const float* __restrict__ q,
                                                 const float* __restrict__ k,
                                                 const float* __restrict__ v,
                                                 const float* __restrict__ wq,
                                                 const float* __restrict__ wk,
                                                 const float* __restrict__ wv,
                                                 const float* __restrict__ wo,
                                                 const int* __restrict__ mask,
                                                 bf16* __restrict__ qb, bf16* __restrict__ kb,
                                                 bf16* __restrict__ vb, bf16* __restrict__ wqb,
                                                 bf16* __restrict__ wkb, bf16* __restrict__ wvb,
                                                 bf16* __restrict__ wob,
                                                 unsigned long long* __restrict__ mbits) {
    if (blockIdx.y == 7) {  // mask pack
        const int nwords = NBATCH * SEQ * (SEQ / 64);
        int wave  = (blockIdx.x * blockDim.x + threadIdx.x) >> 6;
        int lane  = threadIdx.x & 63;
        int nwtot = (gridDim.x * blockDim.x) >> 6;
        for (int w = wave; w < nwords; w += nwtot) {
            int m = mask[(size_t)w * 64 + lane];
            unsigned long long b = __ballot(m != 0);
            if (lane == 0) mbits[w] = b;
        }
        return;
    }
    const float* src; bf16* dst; int n4;
    const int NX4 = (NBATCH * SEQ * DMODEL) / 4, NW4 = (DMODEL * DMODEL) / 4;
    switch (blockIdx.y) {
        case 0: src = q;  dst = qb;  n4 = NX4; break;
        case 1: src = k;  dst = kb;  n4 = NX4; break;
        case 2: src = v;  dst = vb;  n4 = NX4; break;
        case 3: src = wq; dst = wqb; n4 = NW4; break;
        case 4: src = wk; dst = wkb; n4 = NW4; break;
        case 5: src = wv; dst = wvb; n4 = NW4; break;
        default: src = wo; dst = wob; n4 = NW4; break;
    }
    int stride = gridDim.x * blockDim.x;
    for (int i = blockIdx.x * blockDim.x + threadIdx.x; i < n4; i += stride) {
        f32x4 f = ((const f32x4*)src)[i];
        bf16x4 o;
#pragma unroll
        for (int j = 0; j < 4; j++) o[j] = (bf16)f[j];
        ((bf16x4*)dst)[i] = o;
    }
}

// ---------------------------------------------------------------------------
// Kernel 2: QKV projection v16. 128x64 tiles, BK=64, reg-staged T14 pipeline:
// barrier -> ds_write(6 prefetched bf16x8) -> issue next-tile loads ->
// barrier -> 2x(ds_read frags + 8 MFMA). 16 iterations (was 32).
// LDS As[128][72]+Bs[64][72]=27.6KB (72-pad: 2-way banks, attn-proven).
// z=0:Q (pre-scaled) z=1:K -> [n,h,s,64]; z=2:V -> [n,h,64,s] (operand swap).
// ---------------------------------------------------------------------------
__global__ __launch_bounds__(256) void qkv_gemm(const bf16* __restrict__ Xq,
                                                const bf16* __restrict__ Xk,
                                                const bf16* __restrict__ Xv,
                                                const bf16* __restrict__ Wq,
                                                const bf16* __restrict__ Wk,
                                                const bf16* __restrict__ Wv,
                                                bf16* __restrict__ Qo,
                                                bf16* __restrict__ Ko,
                                                bf16* __restrict__ Vto) {
    __shared__ bf16 As[128 * 72], Bs[64 * 72];
    const int z = blockIdx.z;
    const bf16* A = (z == 0) ? Xq : (z == 1) ? Xk : Xv;
    const bf16* W = (z == 0) ? Wq : (z == 1) ? Wk : Wv;
    const int bm = blockIdx.x * 128, bn = blockIdx.y * 64;
    const int tid = threadIdx.x, wave = tid >> 6, lane = tid & 63;
    const int wm = wave >> 1, wn = wave & 1, lo = lane & 15, hi = lane >> 4;

    const int srow = tid >> 3, sseg = tid & 7;   // 32 rows x 64 cols per round
    const bf16* Ag = A + (size_t)(bm + srow) * DMODEL + sseg * 8;
    const bf16* Bg = W + (size_t)(bn + srow) * DMODEL + sseg * 8;
    bf16* lA = &As[srow * 72 + sseg * 8];
    bf16* lB = &Bs[srow * 72 + sseg * 8];

    f32x4 acc[4][2];
#pragma unroll
    for (int i = 0; i < 4; i++)
#pragma unroll
        for (int j = 0; j < 2; j++) acc[i][j] = 0.0f;

    // prologue: prefetch k-tile 0 into registers (A 4 rounds, B 2 rounds)
    bf16x8 ra[4], rb[2];
#pragma unroll
    for (int i = 0; i < 4; i++) ra[i] = *(const bf16x8*)(Ag + (size_t)(32 * i) * DMODEL);
#pragma unroll
    for (int i = 0; i < 2; i++) rb[i] = *(const bf16x8*)(Bg + (size_t)(32 * i) * DMODEL);

#pragma unroll 1
    for (int k0 = 0; k0 < DMODEL; k0 += 64) {
        __syncthreads();   // all waves done reading LDS from previous iter
#pragma unroll
        for (int i = 0; i < 4; i++) *(bf16x8*)(lA + 32 * i * 72) = ra[i];
#pragma unroll
        for (int i = 0; i < 2; i++) *(bf16x8*)(lB + 32 * i * 72) = rb[i];
        if (k0 + 64 < DMODEL) {  // issue next-tile loads; consumed next iter
#pragma unroll
            for (int i = 0; i < 4; i++)
                ra[i] = *(const bf16x8*)(Ag + k0 + 64 + (size_t)(32 * i) * DMODEL);
#pragma unroll
            for (int i = 0; i < 2; i++)
                rb[i] = *(const bf16x8*)(Bg + k0 + 64 + (size_t)(32 * i) * DMODEL);
        }
        __syncthreads();   // LDS writes visible

#pragma unroll
        for (int kk = 0; kk < 64; kk += 32) {
            bf16x8 a[4], b[2];
#pragma unroll
            for (int t = 0; t < 4; t++)
                a[t] = *(const bf16x8*)&As[(wm * 64 + t * 16 + lo) * 72 + kk + hi * 8];
#pragma unroll
            for (int t = 0; t < 2; t++)
                b[t] = *(const bf16x8*)&Bs[(wn * 32 + t * 16 + lo) * 72 + kk + hi * 8];
            if (z < 2) {
#pragma unroll
                for (int tm = 0; tm < 4; tm++)
#pragma unroll
                    for (int tn = 0; tn < 2; tn++)
                        acc[tm][tn] = mfma16(a[tm], b[tn], acc[tm][tn]);
            } else {
                // transposed accumulate: acc = C^T tile (rows=o, cols=m)
#pragma unroll
                for (int tm = 0; tm < 4; tm++)
#pragma unroll
                    for (int tn = 0; tn < 2; tn++)
                        acc[tm][tn] = mfma16(b[tn], a[tm], acc[tm][tn]);
            }
        }
    }

    if (z < 2) {
        bf16* O = (z == 0) ? Qo : Ko;
        const float qscale = (z == 0) ? 0.18033688f : 1.0f;  // 0.125 * log2(e)
#pragma unroll
        for (int tm = 0; tm < 4; tm++)
#pragma unroll
            for (int tn = 0; tn < 2; tn++)
#pragma unroll
                for (int r = 0; r < 4; r++) {
                    int m = bm + wm * 64 + tm * 16 + hi * 4 + r;
                    int o = bn + wn * 32 + tn * 16 + lo;
                    int nidx = m >> 11, sq = m & 2047;
                    int hh = o >> 6, d = o & 63;
                    O[(((size_t)nidx * NH + hh) * SEQ + sq) * DKH + d] = (bf16)(acc[tm][tn][r] * qscale);
                }
    } else {
        // acc is C^T: row (hi*4+r) -> o (h,d); col (lo) -> m (n,sq).
#pragma unroll
        for (int tm = 0; tm < 4; tm++)
#pragma unroll
            for (int tn = 0; tn < 2; tn++)
#pragma unroll
                for (int r = 0; r < 4; r++) {
                    int o = bn + wn * 32 + tn * 16 + hi * 4 + r;
                    int m = bm + wm * 64 + tm * 16 + lo;
                    int nidx = m >> 11, sq = m & 2047;
                    int hh = o >> 6, d = o & 63;
                    Vto[(((size_t)nidx * NH + hh) * DKH + d) * SEQ + sq] = (bf16)acc[tm][tn][r];
                }
    }
}

// ---------------------------------------------------------------------------
// Kernel 3: flash attention v15 — QBLK=128 + KBLK=128 (two 64-k chains per
// barrier pair). launch_bounds(256,3). Swapped QK^T + in-register softmax.
// K-SPLIT x ksn. LDS Ks[128][72]+Vs[64][136]=35.8KB. Measured floor ~60us.
// ---------------------------------------------------------------------------
__global__ __launch_bounds__(256, 3) void attn_k(const bf16* __restrict__ Q,
                                                 const bf16* __restrict__ K,
                                                 const bf16* __restrict__ Vt,
                                                 const unsigned long long* __restrict__ mbits,
                                                 bf16* __restrict__ Op0,
                                                 bf16* __restrict__ Op1,
                                                 float* __restrict__ Lp,
                                                 int ksrange) {
    __shared__ bf16 Ks[128 * 72];
    __shared__ bf16 Vs[64 * 136];

    const int bid = blockIdx.x;
    const int xcd = bid & 7, j = bid >> 3;        // j: 0..(grid/8-1)
    const int hd = xcd * 4 + (j & 3);             // head index 0..31 (= n*16+h)
    const int qb = (j >> 2) & 15;                 // q-block 0..15 (128 rows each)
    const int ks = j >> 6;                        // k-split index (0..ksn-1)
    const int n = hd >> 4, h = hd & 15;

    const int tid = threadIdx.x, wave = tid >> 6, lane = tid & 63;
    const int lo = lane & 15, hi = lane >> 4;

    const size_t headoff = (size_t)hd * SEQ * DKH;
    const bf16* Qh = Q + headoff;
    const bf16* Kh = K + headoff;
    const bf16* Vh = Vt + headoff;   // [64][2048]

    const int qrowA = qb * 128 + wave * 16 + lo;
    const int qrowB = qrowA + 64;
    const bf16x8 aq0A = *(const bf16x8*)(Qh + (size_t)qrowA * DKH + hi * 8);
    const bf16x8 aq1A = *(const bf16x8*)(Qh + (size_t)qrowA * DKH + 32 + hi * 8);
    const bf16x8 aq0B = *(const bf16x8*)(Qh + (size_t)qrowB * DKH + hi * 8);
    const bf16x8 aq1B = *(const bf16x8*)(Qh + (size_t)qrowB * DKH + 32 + hi * 8);

    bf16x8 ones;
#pragma unroll
    for (int i = 0; i < 8; i++) ones[i] = (bf16)1.0f;

    f32x4 oaccA[4], oaccB[4];
#pragma unroll
    for (int t = 0; t < 4; t++) { oaccA[t] = 0.0f; oaccB[t] = 0.0f; }
    f32x4 laccA; laccA = 0.0f;
    f32x4 laccB; laccB = 0.0f;

    const unsigned long long* mbqA = mbits + ((size_t)n * SEQ + qrowA) * (SEQ / 64);
    const unsigned long long* mbqB = mbits + ((size_t)n * SEQ + qrowB) * (SEQ / 64);

    const int kbeg = ks * ksrange, kend = kbeg + ksrange;

    const int srow = tid >> 3, sseg = tid & 7;   // 32 rows x 64 cols per store round
    const bf16* Kg = Kh + (size_t)srow * DKH + sseg * 8;
    const bf16* Vg = Vh + (size_t)srow * SEQ + sseg * 8;

    // preload first 128-k tile of this k-range into registers
    bf16x8 rk0 = *(const bf16x8*)(Kg + (size_t)(kbeg)      * DKH);
    bf16x8 rk1 = *(const bf16x8*)(Kg + (size_t)(kbeg + 32) * DKH);
    bf16x8 rk2 = *(const bf16x8*)(Kg + (size_t)(kbeg + 64) * DKH);
    bf16x8 rk3 = *(const bf16x8*)(Kg + (size_t)(kbeg + 96) * DKH);
    bf16x8 rv0 = *(const bf16x8*)(Vg + kbeg);
    bf16x8 rv1 = *(const bf16x8*)(Vg + (size_t)32 * SEQ + kbeg);
    bf16x8 rv2 = *(const bf16x8*)(Vg + kbeg + 64);
    bf16x8 rv3 = *(const bf16x8*)(Vg + (size_t)32 * SEQ + kbeg + 64);
    unsigned long long wmA0 = mbqA[(kbeg >> 6)], wmA1 = mbqA[(kbeg >> 6) + 1];
    unsigned long long wmB0 = mbqB[(kbeg >> 6)], wmB1 = mbqB[(kbeg >> 6) + 1];
    unsigned long long wmnA0 = 0, wmnA1 = 0, wmnB0 = 0, wmnB1 = 0;

    union FragU { uint32_t u[4]; bf16x8 v; };

    // one 64-k tile: S^T (both q-subtiles) -> masked exp2 -> pack/permlane ->
    // PV accumulate. koff selects tile row/col base inside Ks/Vs.
    auto tile = [&](int koff, unsigned long long wmA, unsigned long long wmB) {
        unsigned wloA = (unsigned)(wmA >> (hi * 4));
        unsigned whiA = (unsigned)(wmA >> (hi * 4 + 32));
        unsigned wloB = (unsigned)(wmB >> (hi * 4));
        unsigned whiB = (unsigned)(wmB >> (hi * 4 + 32));
        uint32_t pkA[4][2], pkB[4][2];
#pragma unroll
        for (int tn = 0; tn < 4; tn++) {
            const int kr = (koff + tn * 16 + lo) * 72;
            bf16x8 b0 = *(const bf16x8*)&Ks[kr + hi * 8];
            bf16x8 b1 = *(const bf16x8*)&Ks[kr + 32 + hi * 8];
            f32x4 zA; zA = 0.0f;
            zA = mfma16(b0, aq0A, zA);
            zA = mfma16(b1, aq1A, zA);
            f32x4 zB; zB = 0.0f;
            zB = mfma16(b0, aq0B, zB);
            zB = mfma16(b1, aq1B, zB);
            unsigned wsA = ((tn < 2) ? wloA : whiA) >> ((tn & 1) * 16);
            unsigned wsB = ((tn < 2) ? wloB : whiB) >> ((tn & 1) * 16);
            float pvA[4], pvB[4];
#pragma unroll
            for (int r = 0; r < 4; r++) {
                float eA = __builtin_amdgcn_exp2f(zA[r]);
                pvA[r] = ((wsA >> r) & 1u) ? eA : 0.0f;
                float eB = __builtin_amdgcn_exp2f(zB[r]);
                pvB[r] = ((wsB >> r) & 1u) ? eB : 0.0f;
            }
            asm("v_cvt_pk_bf16_f32 %0, %1, %2" : "=v"(pkA[tn][0]) : "v"(pvA[0]), "v"(pvA[1]));
            asm("v_cvt_pk_bf16_f32 %0, %1, %2" : "=v"(pkA[tn][1]) : "v"(pvA[2]), "v"(pvA[3]));
            asm("v_cvt_pk_bf16_f32 %0, %1, %2" : "=v"(pkB[tn][0]) : "v"(pvB[0]), "v"(pvB[1]));
            asm("v_cvt_pk_bf16_f32 %0, %1, %2" : "=v"(pkB[tn][1]) : "v"(pvB[2]), "v"(pvB[3]));
        }

        bf16x8 ap0A, ap1A, ap0B, ap1B;
        {
            uint32_t d00 = pkA[0][0], d02 = pkA[1][0];
            PL32SWAP(d00, d02); PL16SWAP(d00, d02);
            uint32_t d01 = pkA[0][1], d03 = pkA[1][1];
            PL32SWAP(d01, d03); PL16SWAP(d01, d03);
            uint32_t d10 = pkA[2][0], d12 = pkA[3][0];
            PL32SWAP(d10, d12); PL16SWAP(d10, d12);
            uint32_t d11 = pkA[2][1], d13 = pkA[3][1];
            PL32SWAP(d11, d13); PL16SWAP(d11, d13);
            FragU f0, f1;
            f0.u[0] = d00; f0.u[1] = d01; f0.u[2] = d02; f0.u[3] = d03;
            f1.u[0] = d10; f1.u[1] = d11; f1.u[2] = d12; f1.u[3] = d13;
            ap0A = f0.v; ap1A = f1.v;
        }
        {
            uint32_t d00 = pkB[0][0], d02 = pkB[1][0];
            PL32SWAP(d00, d02); PL16SWAP(d00, d02);
            uint32_t d01 = pkB[0][1], d03 = pkB[1][1];
            PL32SWAP(d01, d03); PL16SWAP(d01, d03);
            uint32_t d10 = pkB[2][0], d12 = pkB[3][0];
            PL32SWAP(d10, d12); PL16SWAP(d10, d12);
            uint32_t d11 = pkB[2][1], d13 = pkB[3][1];
            PL32SWAP(d11, d13); PL16SWAP(d11, d13);
            FragU f0, f1;
            f0.u[0] = d00; f0.u[1] = d01; f0.u[2] = d02; f0.u[3] = d03;
            f1.u[0] = d10; f1.u[1] = d11; f1.u[2] = d12; f1.u[3] = d13;
            ap0B = f0.v; ap1B = f1.v;
        }

#pragma unroll
        for (int td = 0; td < 4; td++) {
            bf16x8 b0 = *(const bf16x8*)&Vs[(td * 16 + lo) * 136 + koff + hi * 8];
            bf16x8 b1 = *(const bf16x8*)&Vs[(td * 16 + lo) * 136 + koff + 32 + hi * 8];
            oaccA[td] = mfma16(ap0A, b0, oaccA[td]);
            oaccA[td] = mfma16(ap1A, b1, oaccA[td]);
            oaccB[td] = mfma16(ap0B, b0, oaccB[td]);
            oaccB[td] = mfma16(ap1B, b1, oaccB[td]);
        }
        laccA = mfma16(ap0A, ones, laccA);
        laccA = mfma16(ap1A, ones, laccA);
        laccB = mfma16(ap0B, ones, laccB);
        laccB = mfma16(ap1B, ones, laccB);
    };

#pragma unroll 1
    for (int k0 = kbeg; k0 < kend; k0 += 128) {
        __syncthreads();
        *(bf16x8*)&Ks[(srow)      * 72 + sseg * 8] = rk0;
        *(bf16x8*)&Ks[(srow + 32) * 72 + sseg * 8] = rk1;
        *(bf16x8*)&Ks[(srow + 64) * 72 + sseg * 8] = rk2;
        *(bf16x8*)&Ks[(srow + 96) * 72 + sseg * 8] = rk3;
        *(bf16x8*)&Vs[(srow)      * 136 + sseg * 8]      = rv0;
        *(bf16x8*)&Vs[(srow + 32) * 136 + sseg * 8]      = rv1;
        *(bf16x8*)&Vs[(srow)      * 136 + 64 + sseg * 8] = rv2;
        *(bf16x8*)&Vs[(srow + 32) * 136 + 64 + sseg * 8] = rv3;
        if (k0 + 128 < kend) {  // prefetch next 128-k tile (covered by compute)
            rk0 = *(const bf16x8*)(Kg + (size_t)(k0 + 128) * DKH);
            rk1 = *(const bf16x8*)(Kg + (size_t)(k0 + 160) * DKH);
            rk2 = *(const bf16x8*)(Kg + (size_t)(k0 + 192) * DKH);
            rk3 = *(const bf16x8*)(Kg + (size_t)(k0 + 224) * DKH);
            rv0 = *(const bf16x8*)(Vg + k0 + 128);
            rv1 = *(const bf16x8*)(Vg + (size_t)32 * SEQ + k0 + 128);
            rv2 = *(const bf16x8*)(Vg + k0 + 192);
            rv3 = *(const bf16x8*)(Vg + (size_t)32 * SEQ + k0 + 192);
            wmnA0 = mbqA[(k0 >> 6) + 2]; wmnA1 = mbqA[(k0 >> 6) + 3];
            wmnB0 = mbqB[(k0 >> 6) + 2]; wmnB1 = mbqB[(k0 >> 6) + 3];
        }
        __syncthreads();

        tile(0,  wmA0, wmB0);   // two independent chains inside one barrier
        tile(64, wmA1, wmB1);   // section: scheduler overlaps S1 with SM0

        wmA0 = wmnA0; wmA1 = wmnA1;
        wmB0 = wmnB0; wmB1 = wmnB1;
    }

    // epilogue: write bf16 partial O [n,q,h*64+d] and f32 partial l [ks][n,h,q]
    bf16* Op = ks ? Op1 : Op0;
#pragma unroll
    for (int td = 0; td < 4; td++)
#pragma unroll
        for (int r = 0; r < 4; r++) {
            int qA = qb * 128 + wave * 16 + hi * 4 + r;
            int qB = qA + 64;
            int d = td * 16 + lo;
            Op[((size_t)n * SEQ + qA) * DMODEL + h * 64 + d] = (bf16)oaccA[td][r];
            Op[((size_t)n * SEQ + qB) * DMODEL + h * 64 + d] = (bf16)oaccB[td][r];
        }
    if (lo == 0) {
#pragma unroll
        for (int r = 0; r < 4; r++) {
            int qA = qb * 128 + wave * 16 + hi * 4 + r;
            int qB = qA + 64;
            size_t base = (size_t)ks * (NBATCH * NH * SEQ) + ((size_t)(n * NH + h) * SEQ);
            Lp[base + qA] = laccA[r];
            Lp[base + qB] = laccB[r];
        }
    }
}

// ---------------------------------------------------------------------------
// Kernel 4: out = ((o0+o1)/sum(l)) @ Wo^T + bo, FP32 out. v16: 128x64 tiles,
// BK=64, reg-staged T14 pipeline, merge fused into A-staging (h = k0>>6
// uniform per 64-wide K-tile). 16 iterations.
// ---------------------------------------------------------------------------
__global__ __launch_bounds__(256) void out_gemm(const bf16* __restrict__ o0,
                                                const bf16* __restrict__ o1,
                                                const float* __restrict__ lp,
                                                const bf16* __restrict__ W,
                                                const float* __restrict__ bias,
                                                float* __restrict__ Out) {
    __shared__ bf16 As[128 * 72], Bs[64 * 72];
    const int bm = blockIdx.x * 128, bn = blockIdx.y * 64;
    const int tid = threadIdx.x, wave = tid >> 6, lane = tid & 63;
    const int wm = wave >> 1, wn = wave & 1, lo = lane & 15, hi = lane >> 4;

    const int srow = tid >> 3, sseg = tid & 7;
    const int NL = NBATCH * NH * SEQ;
    int mrow[4]; size_t aoff[4]; int lib[4];
#pragma unroll
    for (int i = 0; i < 4; i++) {
        mrow[i] = bm + srow + 32 * i;
        aoff[i] = (size_t)mrow[i] * DMODEL + sseg * 8;
        lib[i]  = (mrow[i] >> 11) * (NH * SEQ) + (mrow[i] & 2047);
    }
    const bf16* Bg = W + (size_t)(bn + srow) * DMODEL + sseg * 8;
    bf16* lA = &As[srow * 72 + sseg * 8];
    bf16* lB = &Bs[srow * 72 + sseg * 8];

    f32x4 acc[4][2];
#pragma unroll
    for (int i = 0; i < 4; i++)
#pragma unroll
        for (int j = 0; j < 2; j++) acc[i][j] = 0.0f;

    // prologue: prefetch k-tile 0 (h = 0)
    bf16x8 px[4], py[4], pb[2];
    float pla[4], plb[4];
#pragma unroll
    for (int i = 0; i < 4; i++) {
        px[i] = *(const bf16x8*)(o0 + aoff[i]);
        py[i] = *(const bf16x8*)(o1 + aoff[i]);
        pla[i] = lp[lib[i]];
        plb[i] = lp[NL + lib[i]];
    }
#pragma unroll
    for (int i = 0; i < 2; i++) pb[i] = *(const bf16x8*)(Bg + (size_t)(32 * i) * DMODEL);

#pragma unroll 1
    for (int k0 = 0; k0 < DMODEL; k0 += 64) {
        __syncthreads();
#pragma unroll
        for (int i = 0; i < 4; i++) {
            float rl = 1.0f / (pla[i] + plb[i]);
            bf16x8 wa;
#pragma unroll
            for (int jj = 0; jj < 8; jj++)
                wa[jj] = (bf16)(((float)px[i][jj] + (float)py[i][jj]) * rl);
            *(bf16x8*)(lA + 32 * i * 72) = wa;
        }
#pragma unroll
        for (int i = 0; i < 2; i++) *(bf16x8*)(lB + 32 * i * 72) = pb[i];
        if (k0 + 64 < DMODEL) {  // prefetch next k-tile (h = (k0+64)>>6)
            int h = (k0 + 64) >> 6;
#pragma unroll
            for (int i = 0; i < 4; i++) {
                px[i] = *(const bf16x8*)(o0 + aoff[i] + k0 + 64);
                py[i] = *(const bf16x8*)(o1 + aoff[i] + k0 + 64);
                int li = lib[i] + h * SEQ;
                pla[i] = lp[li];
                plb[i] = lp[NL + li];
            }
#pragma unroll
            for (int i = 0; i < 2; i++)
                pb[i] = *(const bf16x8*)(Bg + k0 + 64 + (size_t)(32 * i) * DMODEL);
        }
        __syncthreads();

#pragma unroll
        for (int kk = 0; kk < 64; kk += 32) {
            bf16x8 a[4], b[2];
#pragma unroll
            for (int t = 0; t < 4; t++)
                a[t] = *(const bf16x8*)&As[(wm * 64 + t * 16 + lo) * 72 + kk + hi * 8];
#pragma unroll
            for (int t = 0; t < 2; t++)
                b[t] = *(const bf16x8*)&Bs[(wn * 32 + t * 16 + lo) * 72 + kk + hi * 8];
#pragma unroll
            for (int tm = 0; tm < 4; tm++)
#pragma unroll
                for (int tn = 0; tn < 2; tn++)
                    acc[tm][tn] = mfma16(a[tm], b[tn], acc[tm][tn]);
        }
    }

#pragma unroll
    for (int tm = 0; tm < 4; tm++)
#pragma unroll
        for (int tn = 0; tn < 2; tn++) {
            int o = bn + wn * 32 + tn * 16 + lo;
            float bv = bias[o];
#pragma unroll
            for (int r = 0; r < 4; r++) {
                int m = bm + wm * 64 + tm * 16 + hi * 4 + r;
                Out[(size_t)m * DMODEL + o] = acc[tm][tn][r] + bv;
            }
        }
}

// ---------------------------------------------------------------------------
extern "C" void kernel_launch(void* const* d_in, const int* in_sizes, int n_in,
                              void* d_out, int out_size, void* d_ws, size_t ws_size,
                              hipStream_t stream) {
    const float* value = (const float*)d_in[0];
    const float* key   = (const float*)d_in[1];
    const float* query = (const float*)d_in[2];
    const int*   mask  = (const int*)d_in[3];
    const float* Wq    = (const float*)d_in[4];
    const float* Wk    = (const float*)d_in[5];
    const float* Wv    = (const float*)d_in[6];
    const float* Wo    = (const float*)d_in[7];
    const float* bo    = (const float*)d_in[8];
    float* out = (float*)d_out;

    char* ws = (char*)d_ws;
    bf16* Qws = (bf16*)(ws);                         // 8 MB [n,h,s,64]
    bf16* Kws = (bf16*)(ws + (8u  << 20));           // 8 MB [n,h,s,64]
    bf16* Vt  = (bf16*)(ws + (16u << 20));           // 8 MB [n,h,64,s]
    bf16* Xqb = (bf16*)(ws + (24u << 20));           // 8 MB; after qkv: o_part0
    bf16* Xkb = (bf16*)(ws + (32u << 20));           // 8 MB; after qkv: o_part1
    bf16* Xvb = (bf16*)(ws + (40u << 20));           // 8 MB
    bf16* Wqb = (bf16*)(ws + (48u << 20));           // 2 MB; after qkv: l_part (512KB)
    bf16* Wkb = (bf16*)(ws + (50u << 20));           // 2 MB
    bf16* Wvb = (bf16*)(ws + (52u << 20));           // 2 MB
    bf16* Wob = (bf16*)(ws + (54u << 20));           // 2 MB (live until out_gemm)
    unsigned long long* mbits = (unsigned long long*)(ws + (56u << 20));  // 1 MB
    bf16*  Op0 = Xqb;
    bf16*  Op1 = Xkb;
    float* Lp  = (float*)Wqb;

    // K-SPLIT x2 (x4 measured NULL in R4 — attn is not TLP-bound)
    const int  ksn     = 2;
    const int  ksrange = SEQ / ksn;
    const int  attn_grid = 32 * 16 * ksn;            // heads * q-blocks * k-splits

    cvt_all_k<<<dim3(1024, 8), 256, 0, stream>>>(query, key, value, Wq, Wk, Wv, Wo, mask,
                                                 Xqb, Xkb, Xvb, Wqb, Wkb, Wvb, Wob, mbits);
    qkv_gemm<<<dim3(32, 16, 3), 256, 0, stream>>>(Xqb, Xkb, Xvb, Wqb, Wkb, Wvb, Qws, Kws, Vt);
    attn_k<<<attn_grid, 256, 0, stream>>>(Qws, Kws, Vt, mbits, Op0, Op1, Lp, ksrange);
    out_gemm<<<dim3(32, 16), 256, 0, stream>>>(Op0, Op1, Lp, Wob, bo, out);
}